// Round 2
// baseline (1976.805 us; speedup 1.0000x reference)
//
#include <hip/hip_runtime.h>
#include <hip/hip_bf16.h>
#include <cstdint>
#include <cstddef>

#define DIM_ 2048
#define HV_ 32
#define HK_ 16
#define DK_ 128
#define DV_ 128
#define KW_ 4
#define KEY_DIM_ 2048
#define VAL_DIM_ 4096
#define CONV_DIM_ 8192
#define B_ 2
#define T_ 2048
#define BT_ 4096   /* B*T rows */

typedef short s8v __attribute__((ext_vector_type(8)));
typedef float f4v __attribute__((ext_vector_type(4)));

__device__ __forceinline__ unsigned short f2b(float f) {
    union { float f; unsigned u; } c; c.f = f;
    unsigned u = c.u;
    return (unsigned short)((u + 0x7fffu + ((u >> 16) & 1u)) >> 16);
}
__device__ __forceinline__ float b2f(unsigned short s) {
    union { unsigned u; float f; } c; c.u = ((unsigned)s) << 16;
    return c.f;
}
__device__ __forceinline__ float silu(float x) { return x / (1.f + expf(-x)); }

// ---------------- cast f32 -> bf16 (8 elems/thread) ----------------
__global__ void cast_bf16_k(const float* __restrict__ in, unsigned short* __restrict__ out, int n8) {
    int i = blockIdx.x * blockDim.x + threadIdx.x;
    if (i >= n8) return;
    int base = i * 8;
    f4v a = *(const f4v*)(in + base);
    f4v b = *(const f4v*)(in + base + 4);
    s8v o;
    o[0] = (short)f2b(a[0]); o[1] = (short)f2b(a[1]); o[2] = (short)f2b(a[2]); o[3] = (short)f2b(a[3]);
    o[4] = (short)f2b(b[0]); o[5] = (short)f2b(b[1]); o[6] = (short)f2b(b[2]); o[7] = (short)f2b(b[3]);
    *(s8v*)(out + base) = o;
}

// ---------------- transpose + cast f32[R][C] -> bf16[C][R] ----------------
__global__ void transpose_cast_k(const float* __restrict__ in, unsigned short* __restrict__ out,
                                 int R, int C) {
    __shared__ float tile[32][33];
    int c0 = blockIdx.x * 32, r0 = blockIdx.y * 32;
    int tx = threadIdx.x & 31, ty = threadIdx.x >> 5; // 32 x 8
#pragma unroll
    for (int j = 0; j < 32; j += 8)
        tile[ty + j][tx] = in[(size_t)(r0 + ty + j) * C + c0 + tx];
    __syncthreads();
#pragma unroll
    for (int j = 0; j < 32; j += 8)
        out[(size_t)(c0 + ty + j) * R + r0 + tx] = f2b(tile[tx][ty + j]);
}

// ---------------- bf16 GEMM: C[M,N] = A[M,K] * BT[N,K]^T ----------------
// m97 structure: 128x128 tile, BK=64, 4 waves (2x2), global_load_lds w16,
// linear LDS dest + inverse-swizzled source + swizzled ds_read_b128 (T2).
template <int OUT_BF16>
__global__ __launch_bounds__(256) void gemm_bt_k(const unsigned short* __restrict__ A,
                                                 const unsigned short* __restrict__ BT,
                                                 void* __restrict__ Cv,
                                                 int M, int N, int K) {
    __shared__ __attribute__((aligned(16))) unsigned short As[128 * 64];
    __shared__ __attribute__((aligned(16))) unsigned short Bs[128 * 64];
    const int tid = threadIdx.x;
    const int wid = tid >> 6, lane = tid & 63;
    const int wm = wid >> 1, wn = wid & 1;
    const int m0 = blockIdx.y * 128, n0 = blockIdx.x * 128;

    f4v acc[4][4];
#pragma unroll
    for (int i = 0; i < 4; i++)
#pragma unroll
        for (int j = 0; j < 4; j++) acc[i][j] = (f4v){0.f, 0.f, 0.f, 0.f};

    const int rowA = tid >> 3;          // 0..31 per pass
    const int cb   = (tid & 7) << 4;    // column byte 0..112

    for (int kt = 0; kt < K; kt += 64) {
#pragma unroll
        for (int i = 0; i < 4; i++) {
            int row = i * 32 + rowA;
            int scb = cb ^ ((row & 7) << 4);            // inverse swizzle on source
            const unsigned short* ga = A  + (size_t)(m0 + row) * K + kt + (scb >> 1);
            const unsigned short* gb = BT + (size_t)(n0 + row) * K + kt + (scb >> 1);
            char* la = (char*)As + i * 4096 + (wid << 10);  // wave-uniform LDS base
            char* lb = (char*)Bs + i * 4096 + (wid << 10);
            __builtin_amdgcn_global_load_lds(
                (const __attribute__((address_space(1))) unsigned int*)ga,
                (__attribute__((address_space(3))) unsigned int*)la, 16, 0, 0);
            __builtin_amdgcn_global_load_lds(
                (const __attribute__((address_space(1))) unsigned int*)gb,
                (__attribute__((address_space(3))) unsigned int*)lb, 16, 0, 0);
        }
        __syncthreads();
#pragma unroll
        for (int kk = 0; kk < 2; kk++) {
            s8v af[4], bfr[4];
#pragma unroll
            for (int mi = 0; mi < 4; mi++) {
                int row = wm * 64 + mi * 16 + (lane & 15);
                int byteoff = (row << 7) + ((kk * 64 + ((lane >> 4) << 4)) ^ ((row & 7) << 4));
                af[mi] = *(const s8v*)((const char*)As + byteoff);
            }
#pragma unroll
            for (int ni = 0; ni < 4; ni++) {
                int row = wn * 64 + ni * 16 + (lane & 15);
                int byteoff = (row << 7) + ((kk * 64 + ((lane >> 4) << 4)) ^ ((row & 7) << 4));
                bfr[ni] = *(const s8v*)((const char*)Bs + byteoff);
            }
#pragma unroll
            for (int mi = 0; mi < 4; mi++)
#pragma unroll
                for (int ni = 0; ni < 4; ni++)
                    acc[mi][ni] = __builtin_amdgcn_mfma_f32_16x16x32_bf16(
                        af[mi], bfr[ni], acc[mi][ni], 0, 0, 0);
        }
        __syncthreads();
    }
    // epilogue: D col = lane&15, row = (lane>>4)*4 + r
#pragma unroll
    for (int mi = 0; mi < 4; mi++) {
#pragma unroll
        for (int ni = 0; ni < 4; ni++) {
            int row = m0 + wm * 64 + mi * 16 + ((lane >> 4) << 2);
            int col = n0 + wn * 64 + ni * 16 + (lane & 15);
#pragma unroll
            for (int r = 0; r < 4; r++) {
                float v = acc[mi][ni][r];
                if (OUT_BF16)
                    ((unsigned short*)Cv)[(size_t)(row + r) * N + col] = f2b(v);
                else
                    ((float*)Cv)[(size_t)(row + r) * N + col] = v;
            }
        }
    }
}

// ---------------- a,b small GEMM + g/beta ----------------
__global__ __launch_bounds__(256) void ab_gbeta_k(const float* __restrict__ x,
                                                  const float* __restrict__ Wa,
                                                  const float* __restrict__ Wb,
                                                  const float* __restrict__ dt_bias,
                                                  const float* __restrict__ A_log,
                                                  float* __restrict__ g, float* __restrict__ beta) {
    __shared__ float xr[2048];
    __shared__ float ps[256];
    int row = blockIdx.x;
    int tid = threadIdx.x;
    const float* xp = x + (size_t)row * 2048;
    *(f4v*)&xr[tid * 8]     = *(const f4v*)&xp[tid * 8];
    *(f4v*)&xr[tid * 8 + 4] = *(const f4v*)&xp[tid * 8 + 4];
    __syncthreads();
    int colc = tid & 63, part = tid >> 6;
    const float* W = (colc < 32) ? Wa : Wb;
    int cc = colc & 31;
    float acc = 0.f;
    int k0 = part * 512;
#pragma unroll 8
    for (int k = k0; k < k0 + 512; k++) acc += xr[k] * W[(size_t)k * 32 + cc];
    ps[tid] = acc;
    __syncthreads();
    if (tid < 64) {
        float tot = ps[tid] + ps[tid + 64] + ps[tid + 128] + ps[tid + 192];
        if (tid < 32) {
            float av = tot + dt_bias[tid];
            float sp = (av > 20.f) ? av : log1pf(expf(av));
            g[(size_t)row * 32 + tid] = -expf(A_log[tid]) * sp;
        } else {
            beta[(size_t)row * 32 + (tid - 32)] = 1.f / (1.f + expf(-tot));
        }
    }
}

// ---------------- conv + silu + l2norm + split (bf16 outputs) ----------------
__global__ void conv_fused_k(const unsigned short* __restrict__ mixp,
                             const float* __restrict__ convw,
                             unsigned short* __restrict__ qn, unsigned short* __restrict__ kn,
                             unsigned short* __restrict__ vv) {
    int btid = blockIdx.x;      // 0..4095 == b*T+t
    int chunk = blockIdx.y;     // 0..63
    int d = threadIdx.x;        // 0..127
    int c = chunk * 128 + d;
    int t = btid & (T_ - 1);
    float w0 = convw[c * 4 + 0], w1 = convw[c * 4 + 1], w2 = convw[c * 4 + 2], w3 = convw[c * 4 + 3];
    const unsigned short* base = mixp + (size_t)btid * CONV_DIM_ + c;
    float acc = b2f(base[0]) * w3;
    if (t >= 1) acc += b2f(base[-CONV_DIM_]) * w2;
    if (t >= 2) acc += b2f(base[-2 * CONV_DIM_]) * w1;
    if (t >= 3) acc += b2f(base[-3 * CONV_DIM_]) * w0;
    float val = silu(acc);
    if (chunk < 32) {
        float ss = val * val;
#pragma unroll
        for (int m = 1; m < 64; m <<= 1) ss += __shfl_xor(ss, m);
        __shared__ float sred[2];
        if ((d & 63) == 0) sred[d >> 6] = ss;
        __syncthreads();
        float scale = rsqrtf(sred[0] + sred[1] + 1e-6f);
        if (chunk < 16) {
            qn[((size_t)btid * HK_ + chunk) * DK_ + d] = f2b(val * scale * 0.08838834764831845f);
        } else {
            kn[((size_t)btid * HK_ + (chunk - 16)) * DK_ + d] = f2b(val * scale);
        }
    } else {
        vv[(size_t)btid * VAL_DIM_ + (c - VAL_DIM_)] = f2b(val);
    }
}

// ---------------- gated delta-rule recurrence ----------------
// grid: B*HV*(DV/32) = 256 blocks; block 256 = 32 cols x 8 k-groups.
__global__ __launch_bounds__(256) void recurrence_k(const unsigned short* __restrict__ qn,
                                                    const unsigned short* __restrict__ kn,
                                                    const unsigned short* __restrict__ vv,
                                                    const float* __restrict__ g,
                                                    const float* __restrict__ beta,
                                                    float* __restrict__ o) {
    int bi = blockIdx.x;
    int vblk = bi & 3;
    int h = (bi >> 2) & 31;
    int b = bi >> 7;
    int tid = threadIdx.x;
    int j = tid >> 3, kg = tid & 7;
    int col = vblk * 32 + j;
    int hk = h >> 1;

    float S[16];
#pragma unroll
    for (int e = 0; e < 16; e++) S[e] = 0.f;

    for (int t = 0; t < T_; t++) {
        size_t btid = (size_t)b * T_ + t;
        size_t rq = (btid * HK_ + hk) * DK_ + kg * 16;
        s8v k8a = *(const s8v*)(kn + rq);
        s8v k8b = *(const s8v*)(kn + rq + 8);
        s8v q8a = *(const s8v*)(qn + rq);
        s8v q8b = *(const s8v*)(qn + rq + 8);
        float kf[16], qf[16];
#pragma unroll
        for (int i = 0; i < 8; i++) {
            kf[i] = b2f((unsigned short)k8a[i]);
            kf[i + 8] = b2f((unsigned short)k8b[i]);
            qf[i] = b2f((unsigned short)q8a[i]);
            qf[i + 8] = b2f((unsigned short)q8b[i]);
        }
        size_t rh = btid * HV_ + h;
        float eg = expf(g[rh]);
        float bt = beta[rh];
        float vt = b2f(vv[rh * DV_ + col]);

        float p = 0.f;
#pragma unroll
        for (int e = 0; e < 16; e++) p += kf[e] * S[e];
        p += __shfl_xor(p, 1); p += __shfl_xor(p, 2); p += __shfl_xor(p, 4);

        float u = (vt - eg * p) * bt;

        float op = 0.f;
#pragma unroll
        for (int e = 0; e < 16; e++) {
            S[e] = eg * S[e] + kf[e] * u;
            op += qf[e] * S[e];
        }
        op += __shfl_xor(op, 1); op += __shfl_xor(op, 2); op += __shfl_xor(op, 4);
        if (kg == 0) o[rh * DV_ + col] = op;
    }
}

// ---------------- gated RMSNorm + silu(z) gate -> bf16 ----------------
__global__ void norm_gate_k(const float* __restrict__ o, const unsigned short* __restrict__ z,
                            const float* __restrict__ nw, unsigned short* __restrict__ onb) {
    int bth = blockIdx.x;  // (b*T+t)*HV + h
    int d = threadIdx.x;   // 0..127
    float val = o[(size_t)bth * DV_ + d];
    float ss = val * val;
#pragma unroll
    for (int m = 1; m < 64; m <<= 1) ss += __shfl_xor(ss, m);
    __shared__ float sred[2];
    if ((d & 63) == 0) sred[d >> 6] = ss;
    __syncthreads();
    float var = (sred[0] + sred[1]) * (1.f / 128.f);
    float zn = b2f(z[(size_t)bth * DV_ + d]);
    float on = val * rsqrtf(var + 1e-6f) * nw[d] * silu(zn);
    onb[(size_t)bth * DV_ + d] = f2b(on);
}

// ---------------- launch ----------------
// Workspace regions (aliased; peak ~209 MiB):
//   A 64 MiB : mixp (bf16 4096x8192)      -> obuf (f32 4096x4096)
//   B 32 MiB : xb   (bf16 4096x2048)      -> onb  (bf16 4096x4096)
//   C 32 MiB : WqkvT(bf16 8192x2048)      -> WoutT(bf16 2048x4096, 16 MiB)
//   D 16 MiB : WzT  (bf16 4096x2048)
//   E 32 MiB : qn+kn (bf16, 16+16)        -> zb   (bf16 4096x4096)
//   F 32 MiB : vv   (bf16 4096x4096)
//   G  1 MiB : g, beta (f32 4096x32 each)
extern "C" void kernel_launch(void* const* d_in, const int* in_sizes, int n_in,
                              void* d_out, int out_size, void* d_ws, size_t ws_size,
                              hipStream_t stream) {
    const float* x      = (const float*)d_in[0];
    const float* W_qkv  = (const float*)d_in[1];
    const float* W_z    = (const float*)d_in[2];
    const float* W_a    = (const float*)d_in[3];
    const float* W_b    = (const float*)d_in[4];
    const float* W_out  = (const float*)d_in[5];
    const float* conv_w = (const float*)d_in[6];
    const float* dt_bias= (const float*)d_in[7];
    const float* A_log  = (const float*)d_in[8];
    const float* norm_w = (const float*)d_in[9];

    char* w = (char*)d_ws;
    size_t off = 0;
    auto alloc = [&](size_t bytes) { char* p = w + off; off += (bytes + 255) & ~(size_t)255; return p; };

    char* regA = alloc((size_t)BT_ * CONV_DIM_ * 2);   // 64 MiB
    char* regB = alloc((size_t)BT_ * DIM_ * 2 * 2);    // 32 MiB (xb 16 -> onb 32; reserve 32)
    char* regC = alloc((size_t)CONV_DIM_ * DIM_ * 2);  // 32 MiB
    char* regD = alloc((size_t)VAL_DIM_ * DIM_ * 2);   // 16 MiB
    char* regE = alloc((size_t)BT_ * KEY_DIM_ * 2 * 2);// 32 MiB (qn+kn -> zb)
    char* regF = alloc((size_t)BT_ * VAL_DIM_ * 2);    // 32 MiB
    char* regG = alloc((size_t)BT_ * HV_ * 4 * 2);     //  1 MiB

    unsigned short* mixp  = (unsigned short*)regA;
    float*          obuf  = (float*)regA;
    unsigned short* xb    = (unsigned short*)regB;
    unsigned short* onb   = (unsigned short*)regB;
    unsigned short* WqkvT = (unsigned short*)regC;
    unsigned short* WoutT = (unsigned short*)regC;
    unsigned short* WzT   = (unsigned short*)regD;
    unsigned short* qn    = (unsigned short*)regE;
    unsigned short* kn    = (unsigned short*)(regE + (size_t)BT_ * KEY_DIM_ * 2);
    unsigned short* zb    = (unsigned short*)regE;
    unsigned short* vv    = (unsigned short*)regF;
    float*          gbuf  = (float*)regG;
    float*          bbuf  = (float*)(regG + (size_t)BT_ * HV_ * 4);

    // 1. cast x -> bf16
    cast_bf16_k<<<(BT_ * DIM_ / 8 + 255) / 256, 256, 0, stream>>>(x, xb, BT_ * DIM_ / 8);
    // 2. weight transposes (qkv, z)
    transpose_cast_k<<<dim3(CONV_DIM_ / 32, DIM_ / 32), 256, 0, stream>>>(W_qkv, WqkvT, DIM_, CONV_DIM_);
    transpose_cast_k<<<dim3(VAL_DIM_ / 32, DIM_ / 32), 256, 0, stream>>>(W_z, WzT, DIM_, VAL_DIM_);
    // 3. qkv GEMM -> mixp (A)
    gemm_bt_k<1><<<dim3(CONV_DIM_ / 128, BT_ / 128), 256, 0, stream>>>(xb, WqkvT, mixp, BT_, CONV_DIM_, DIM_);
    // 4. W_out transpose into C (WqkvT dead)
    transpose_cast_k<<<dim3(DIM_ / 32, VAL_DIM_ / 32), 256, 0, stream>>>(W_out, WoutT, VAL_DIM_, DIM_);
    // 5. a/b + g/beta
    ab_gbeta_k<<<BT_, 256, 0, stream>>>(x, W_a, W_b, dt_bias, A_log, gbuf, bbuf);
    // 6. conv + silu + l2norm + split -> qn,kn (E), vv (F)
    conv_fused_k<<<dim3(BT_, CONV_DIM_ / 128), 128, 0, stream>>>(mixp, conv_w, qn, kn, vv);
    // 7. recurrence -> obuf (A; mixp dead)
    recurrence_k<<<B_ * HV_ * (DV_ / 32), 256, 0, stream>>>(qn, kn, vv, gbuf, bbuf, obuf);
    // 8. z GEMM -> zb (E; qn/kn dead)
    gemm_bt_k<1><<<dim3(VAL_DIM_ / 128, BT_ / 128), 256, 0, stream>>>(xb, WzT, zb, BT_, VAL_DIM_, DIM_);
    // 9. norm + gate -> onb (B; xb dead)
    norm_gate_k<<<BT_ * HV_, 128, 0, stream>>>(obuf, zb, norm_w, onb);
    // 10. output GEMM -> d_out
    gemm_bt_k<0><<<dim3(DIM_ / 128, BT_ / 128), 256, 0, stream>>>(onb, WoutT, d_out, BT_, DIM_, VAL_DIM_);
}

// Round 4
// 955.212 us; speedup vs baseline: 2.0695x; 2.0695x over previous
//
#include <hip/hip_runtime.h>
#include <hip/hip_bf16.h>
#include <cstdint>
#include <cstddef>

#define DIM_ 2048
#define HV_ 32
#define HK_ 16
#define DK_ 128
#define DV_ 128
#define KW_ 4
#define KEY_DIM_ 2048
#define VAL_DIM_ 4096
#define CONV_DIM_ 8192
#define B_ 2
#define T_ 2048
#define BT_ 4096
#define CH_ 64
#define NC_ (T_ / CH_)

typedef short s8v __attribute__((ext_vector_type(8)));
typedef float f4v __attribute__((ext_vector_type(4)));

__device__ __forceinline__ unsigned short f2b(float f) {
    union { float f; unsigned u; } c; c.f = f;
    unsigned u = c.u;
    return (unsigned short)((u + 0x7fffu + ((u >> 16) & 1u)) >> 16);
}
__device__ __forceinline__ float b2f(unsigned short s) {
    union { unsigned u; float f; } c; c.u = ((unsigned)s) << 16;
    return c.f;
}
__device__ __forceinline__ unsigned int pk2(float a, float b) {
    return (unsigned)f2b(a) | ((unsigned)f2b(b) << 16);
}
__device__ __forceinline__ float silu(float x) { return x / (1.f + expf(-x)); }

// ---------------- cast f32 -> bf16 ----------------
__global__ void cast_bf16_k(const float* __restrict__ in, unsigned short* __restrict__ out, int n8) {
    int i = blockIdx.x * blockDim.x + threadIdx.x;
    if (i >= n8) return;
    int base = i * 8;
    f4v a = *(const f4v*)(in + base);
    f4v b = *(const f4v*)(in + base + 4);
    s8v o;
    o[0] = (short)f2b(a[0]); o[1] = (short)f2b(a[1]); o[2] = (short)f2b(a[2]); o[3] = (short)f2b(a[3]);
    o[4] = (short)f2b(b[0]); o[5] = (short)f2b(b[1]); o[6] = (short)f2b(b[2]); o[7] = (short)f2b(b[3]);
    *(s8v*)(out + base) = o;
}

// ---------------- transpose + cast ----------------
__global__ void transpose_cast_k(const float* __restrict__ in, unsigned short* __restrict__ out,
                                 int R, int C) {
    __shared__ float tile[32][33];
    int c0 = blockIdx.x * 32, r0 = blockIdx.y * 32;
    int tx = threadIdx.x & 31, ty = threadIdx.x >> 5;
#pragma unroll
    for (int j = 0; j < 32; j += 8)
        tile[ty + j][tx] = in[(size_t)(r0 + ty + j) * C + c0 + tx];
    __syncthreads();
#pragma unroll
    for (int j = 0; j < 32; j += 8)
        out[(size_t)(c0 + ty + j) * R + r0 + tx] = f2b(tile[tx][ty + j]);
}

// ---------------- bf16 GEMM: C[M,N] = A[M,K] * BT[N,K]^T ----------------
template <int OUT_BF16>
__global__ __launch_bounds__(256) void gemm_bt_k(const unsigned short* __restrict__ A,
                                                 const unsigned short* __restrict__ BT,
                                                 void* __restrict__ Cv,
                                                 int M, int N, int K) {
    __shared__ __attribute__((aligned(16))) unsigned short As[128 * 64];
    __shared__ __attribute__((aligned(16))) unsigned short Bs[128 * 64];
    const int tid = threadIdx.x;
    const int wid = tid >> 6, lane = tid & 63;
    const int wm = wid >> 1, wn = wid & 1;
    const int m0 = blockIdx.y * 128, n0 = blockIdx.x * 128;

    f4v acc[4][4];
#pragma unroll
    for (int i = 0; i < 4; i++)
#pragma unroll
        for (int j = 0; j < 4; j++) acc[i][j] = (f4v){0.f, 0.f, 0.f, 0.f};

    const int rowA = tid >> 3;
    const int cb   = (tid & 7) << 4;

    for (int kt = 0; kt < K; kt += 64) {
#pragma unroll
        for (int i = 0; i < 4; i++) {
            int row = i * 32 + rowA;
            int scb = cb ^ ((row & 7) << 4);
            const unsigned short* ga = A  + (size_t)(m0 + row) * K + kt + (scb >> 1);
            const unsigned short* gb = BT + (size_t)(n0 + row) * K + kt + (scb >> 1);
            char* la = (char*)As + i * 4096 + (wid << 10);
            char* lb = (char*)Bs + i * 4096 + (wid << 10);
            __builtin_amdgcn_global_load_lds(
                (const __attribute__((address_space(1))) unsigned int*)ga,
                (__attribute__((address_space(3))) unsigned int*)la, 16, 0, 0);
            __builtin_amdgcn_global_load_lds(
                (const __attribute__((address_space(1))) unsigned int*)gb,
                (__attribute__((address_space(3))) unsigned int*)lb, 16, 0, 0);
        }
        __syncthreads();
#pragma unroll
        for (int kk = 0; kk < 2; kk++) {
            s8v af[4], bfr[4];
#pragma unroll
            for (int mi = 0; mi < 4; mi++) {
                int row = wm * 64 + mi * 16 + (lane & 15);
                int byteoff = (row << 7) + ((kk * 64 + ((lane >> 4) << 4)) ^ ((row & 7) << 4));
                af[mi] = *(const s8v*)((const char*)As + byteoff);
            }
#pragma unroll
            for (int ni = 0; ni < 4; ni++) {
                int row = wn * 64 + ni * 16 + (lane & 15);
                int byteoff = (row << 7) + ((kk * 64 + ((lane >> 4) << 4)) ^ ((row & 7) << 4));
                bfr[ni] = *(const s8v*)((const char*)Bs + byteoff);
            }
#pragma unroll
            for (int mi = 0; mi < 4; mi++)
#pragma unroll
                for (int ni = 0; ni < 4; ni++)
                    acc[mi][ni] = __builtin_amdgcn_mfma_f32_16x16x32_bf16(
                        af[mi], bfr[ni], acc[mi][ni], 0, 0, 0);
        }
        __syncthreads();
    }
#pragma unroll
    for (int mi = 0; mi < 4; mi++) {
#pragma unroll
        for (int ni = 0; ni < 4; ni++) {
            int row = m0 + wm * 64 + mi * 16 + ((lane >> 4) << 2);
            int col = n0 + wn * 64 + ni * 16 + (lane & 15);
#pragma unroll
            for (int r = 0; r < 4; r++) {
                float v = acc[mi][ni][r];
                if (OUT_BF16)
                    ((unsigned short*)Cv)[(size_t)(row + r) * N + col] = f2b(v);
                else
                    ((float*)Cv)[(size_t)(row + r) * N + col] = v;
            }
        }
    }
}

// ---------------- a,b small GEMM + g/beta ----------------
__global__ __launch_bounds__(256) void ab_gbeta_k(const float* __restrict__ x,
                                                  const float* __restrict__ Wa,
                                                  const float* __restrict__ Wb,
                                                  const float* __restrict__ dt_bias,
                                                  const float* __restrict__ A_log,
                                                  float* __restrict__ g, float* __restrict__ beta) {
    __shared__ float xr[2048];
    __shared__ float ps[256];
    int row = blockIdx.x;
    int tid = threadIdx.x;
    const float* xp = x + (size_t)row * 2048;
    *(f4v*)&xr[tid * 8]     = *(const f4v*)&xp[tid * 8];
    *(f4v*)&xr[tid * 8 + 4] = *(const f4v*)&xp[tid * 8 + 4];
    __syncthreads();
    int colc = tid & 63, part = tid >> 6;
    const float* W = (colc < 32) ? Wa : Wb;
    int cc = colc & 31;
    float acc = 0.f;
    int k0 = part * 512;
#pragma unroll 8
    for (int k = k0; k < k0 + 512; k++) acc += xr[k] * W[(size_t)k * 32 + cc];
    ps[tid] = acc;
    __syncthreads();
    if (tid < 64) {
        float tot = ps[tid] + ps[tid + 64] + ps[tid + 128] + ps[tid + 192];
        if (tid < 32) {
            float av = tot + dt_bias[tid];
            float sp = (av > 20.f) ? av : log1pf(expf(av));
            g[(size_t)row * 32 + tid] = -expf(A_log[tid]) * sp;
        } else {
            beta[(size_t)row * 32 + (tid - 32)] = 1.f / (1.f + expf(-tot));
        }
    }
}

// ---------------- conv + silu + l2norm + split (bf16 outputs) ----------------
__global__ void conv_fused_k(const unsigned short* __restrict__ mixp,
                             const float* __restrict__ convw,
                             unsigned short* __restrict__ qn, unsigned short* __restrict__ kn,
                             unsigned short* __restrict__ vv) {
    int btid = blockIdx.x;
    int chunk = blockIdx.y;
    int d = threadIdx.x;
    int c = chunk * 128 + d;
    int t = btid & (T_ - 1);
    float w0 = convw[c * 4 + 0], w1 = convw[c * 4 + 1], w2 = convw[c * 4 + 2], w3 = convw[c * 4 + 3];
    const unsigned short* base = mixp + (size_t)btid * CONV_DIM_ + c;
    float acc = b2f(base[0]) * w3;
    if (t >= 1) acc += b2f(base[-CONV_DIM_]) * w2;
    if (t >= 2) acc += b2f(base[-2 * CONV_DIM_]) * w1;
    if (t >= 3) acc += b2f(base[-3 * CONV_DIM_]) * w0;
    float val = silu(acc);
    if (chunk < 32) {
        float ss = val * val;
#pragma unroll
        for (int m = 1; m < 64; m <<= 1) ss += __shfl_xor(ss, m);
        __shared__ float sred[2];
        if ((d & 63) == 0) sred[d >> 6] = ss;
        __syncthreads();
        float scale = rsqrtf(sred[0] + sred[1] + 1e-6f);
        if (chunk < 16) {
            qn[((size_t)btid * HK_ + chunk) * DK_ + d] = f2b(val * scale * 0.08838834764831845f);
        } else {
            kn[((size_t)btid * HK_ + (chunk - 16)) * DK_ + d] = f2b(val * scale);
        }
    } else {
        vv[(size_t)btid * VAL_DIM_ + (c - VAL_DIM_)] = f2b(val);
    }
}

// ================= chunked delta rule: parallel precompute =================
__global__ __launch_bounds__(256) void chunk_pre_k(
    const unsigned short* __restrict__ qn, const unsigned short* __restrict__ kn,
    unsigned short* __restrict__ vv,
    const float* __restrict__ g, const float* __restrict__ beta,
    unsigned short* __restrict__ Wg, unsigned short* __restrict__ Aog,
    unsigned short* __restrict__ knT, float* __restrict__ expG, float* __restrict__ expGr)
{
    const int c = blockIdx.x, h = blockIdx.y, b = blockIdx.z;
    const int hk = h >> 1;
    const int tid = threadIdx.x, wid = tid >> 6, lane = tid & 63;
    const int r15 = lane & 15, g4 = lane >> 4;

    __shared__ __attribute__((aligned(16))) unsigned short Klds[64 * 128];
    __shared__ __attribute__((aligned(16))) unsigned short Xlds[128 * 64]; // Q rows, then V/KwT col-major
    __shared__ float AT[64][68];
    __shared__ float Gl[64], Bl[64], EG[64];

    const size_t t0 = (size_t)b * T_ + (size_t)c * 64;
    const size_t cbk = ((size_t)(b * 32 + h) * 32 + c);

    // phase a: stage K,Q swizzled (FULL 256-byte rows: 4 passes x 16 rows x 16 chunks)
#pragma unroll
    for (int p = 0; p < 4; p++) {
        int row = p * 16 + (tid >> 4);
        int colB = (tid & 15) << 4;
        int sw = colB ^ ((row & 7) << 4);
        s8v kv = *(const s8v*)(kn + ((t0 + row) * HK_ + hk) * DK_ + (colB >> 1));
        *(s8v*)((char*)Klds + row * 256 + sw) = kv;
        s8v qv = *(const s8v*)(qn + ((t0 + row) * HK_ + hk) * DK_ + (colB >> 1));
        *(s8v*)((char*)Xlds + row * 256 + sw) = qv;
    }
    if (tid < 64) {
        Gl[tid] = g[(t0 + tid) * HV_ + h];
        Bl[tid] = beta[(t0 + tid) * HV_ + h];
    }
    __syncthreads();
    if (tid == 0) {
        float s = 0.f;
        for (int i = 0; i < 64; i++) { s += Gl[i]; Gl[i] = s; }
    }
    __syncthreads();
    if (tid < 64) {
        float Gi = Gl[tid], Gn = Gl[63];
        float e1 = expf(Gi), e2 = expf(Gn - Gi);
        EG[tid] = e1;
        expG[cbk * 64 + tid] = e1;
        expGr[cbk * 64 + tid] = e2;
    }
    __syncthreads();

    // phase b: KK = K K^T, QK = Q K^T
    f4v kkv[4], qkv[4];
#pragma unroll
    for (int jt = 0; jt < 4; jt++) { kkv[jt] = (f4v){0,0,0,0}; qkv[jt] = (f4v){0,0,0,0}; }
    const int arow = wid * 16 + r15;
#pragma unroll
    for (int ks = 0; ks < 4; ks++) {
        int abyte = arow * 256 + ((ks * 64 + (g4 << 4)) ^ ((arow & 7) << 4));
        s8v ak = *(const s8v*)((const char*)Klds + abyte);
        s8v aq = *(const s8v*)((const char*)Xlds + abyte);
#pragma unroll
        for (int jt = 0; jt < 4; jt++) {
            int jrow = jt * 16 + r15;
            int bbyte = jrow * 256 + ((ks * 64 + (g4 << 4)) ^ ((jrow & 7) << 4));
            s8v bk = *(const s8v*)((const char*)Klds + bbyte);
            kkv[jt] = __builtin_amdgcn_mfma_f32_16x16x32_bf16(ak, bk, kkv[jt], 0, 0, 0);
            qkv[jt] = __builtin_amdgcn_mfma_f32_16x16x32_bf16(aq, bk, qkv[jt], 0, 0, 0);
        }
    }
    // A build (strictly lower) + Ao write (j<=i); clamp exp arg (used entries have Gd<=0)
#pragma unroll
    for (int jt = 0; jt < 4; jt++) {
#pragma unroll
        for (int r = 0; r < 4; r++) {
            int i = wid * 16 + g4 * 4 + r;
            int j = jt * 16 + r15;
            float em = expf(fminf(Gl[i] - Gl[j], 0.f));
            AT[i][j] = (j < i) ? Bl[i] * em * kkv[jt][r] : 0.f;
            float ao = (j <= i) ? em * qkv[jt][r] : 0.f;
            Aog[cbk * 4096 + i * 64 + j] = f2b(ao);
        }
    }
    __syncthreads();

    // phase c: trisolve (wave 0) || V load+scale, knT write (waves 1-3)
    if (wid == 0) {
        for (int i = 0; i < 64; i++) {
            float s = 0.f;
            for (int j = 0; j < i; j++) s += AT[i][j] * AT[j][lane];
            AT[i][lane] = ((lane == i) ? 1.f : 0.f) - s;
        }
    } else {
        int idx = tid - 64;
        for (int u = idx; u < 1024; u += 192) {
            int row = u >> 4, v0 = (u & 15) << 3;
            s8v vx = *(const s8v*)(vv + (t0 + row) * VAL_DIM_ + h * 128 + v0);
            float bt = Bl[row];
#pragma unroll
            for (int e = 0; e < 8; e++) {
                int v = v0 + e;
                *(unsigned short*)((char*)Xlds + v * 128 + ((row * 2) ^ ((v & 7) << 4))) =
                    f2b(b2f((unsigned short)vx[e]) * bt);
            }
        }
        if ((h & 1) == 0) {
            for (int dk = idx; dk < 128; dk += 192) {
                size_t base = ((size_t)(b * 16 + hk) * 128 + dk) * (size_t)T_ + (size_t)c * 64;
                for (int t = 0; t < 64; t++) {
                    knT[base + t] = *(const unsigned short*)((const char*)Klds + t * 256 + ((dk * 2) ^ ((t & 7) << 4)));
                }
            }
        }
    }
    __syncthreads();

    // phase d: TbV = T @ (beta V)  -> vv in place
    f4v tb[8];
#pragma unroll
    for (int vt = 0; vt < 8; vt++) tb[vt] = (f4v){0,0,0,0};
#pragma unroll
    for (int ks = 0; ks < 2; ks++) {
        s8v ta;
#pragma unroll
        for (int e = 0; e < 8; e++) ta[e] = (short)f2b(AT[arow][ks * 32 + g4 * 8 + e]);
#pragma unroll
        for (int vt = 0; vt < 8; vt++) {
            int v = vt * 16 + r15;
            int bbyte = v * 128 + ((ks * 64 + (g4 << 4)) ^ ((v & 7) << 4));
            s8v bv = *(const s8v*)((const char*)Xlds + bbyte);
            tb[vt] = __builtin_amdgcn_mfma_f32_16x16x32_bf16(ta, bv, tb[vt], 0, 0, 0);
        }
    }
#pragma unroll
    for (int vt = 0; vt < 8; vt++)
#pragma unroll
        for (int r = 0; r < 4; r++) {
            int i = wid * 16 + g4 * 4 + r, v = vt * 16 + r15;
            vv[(t0 + i) * VAL_DIM_ + h * 128 + v] = f2b(tb[vt][r]);
        }
    __syncthreads();

    // phase e: KwT[dk][t] = beta_t e^{G_t} K[t][dk]  (into Xlds)
    if (tid < 128) {
        int dk = tid;
        for (int t = 0; t < 64; t++) {
            float kv = b2f(*(const unsigned short*)((const char*)Klds + t * 256 + ((dk * 2) ^ ((t & 7) << 4))));
            *(unsigned short*)((char*)Xlds + dk * 128 + ((t * 2) ^ ((dk & 7) << 4))) =
                f2b(kv * Bl[t] * EG[t]);
        }
    }
    __syncthreads();

    // phase f: Wmat = T @ Kw
    f4v wm[8];
#pragma unroll
    for (int dt = 0; dt < 8; dt++) wm[dt] = (f4v){0,0,0,0};
#pragma unroll
    for (int ks = 0; ks < 2; ks++) {
        s8v ta;
#pragma unroll
        for (int e = 0; e < 8; e++) ta[e] = (short)f2b(AT[arow][ks * 32 + g4 * 8 + e]);
#pragma unroll
        for (int dt = 0; dt < 8; dt++) {
            int dkr = dt * 16 + r15;
            int bbyte = dkr * 128 + ((ks * 64 + (g4 << 4)) ^ ((dkr & 7) << 4));
            s8v bw = *(const s8v*)((const char*)Xlds + bbyte);
            wm[dt] = __builtin_amdgcn_mfma_f32_16x16x32_bf16(ta, bw, wm[dt], 0, 0, 0);
        }
    }
#pragma unroll
    for (int dt = 0; dt < 8; dt++)
#pragma unroll
        for (int r = 0; r < 4; r++) {
            int i = wid * 16 + g4 * 4 + r, dk = dt * 16 + r15;
            Wg[cbk * 8192 + i * 128 + dk] = f2b(wm[dt][r]);
        }
}

// ================= chunked delta rule: sequential scan =================
__global__ __launch_bounds__(256) void chunk_scan_k(
    const unsigned short* __restrict__ qn, const unsigned short* __restrict__ knT,
    const unsigned short* __restrict__ tbv,
    const unsigned short* __restrict__ Wg, const unsigned short* __restrict__ Aog,
    const float* __restrict__ expG, const float* __restrict__ expGr,
    unsigned short* __restrict__ ob0, unsigned short* __restrict__ ob1)
{
    const int bx = blockIdx.x;
    const int vq = bx & 3, h = (bx >> 2) & 31, b = bx >> 7;
    const int hk = h >> 1;
    const int tid = threadIdx.x, wid = tid >> 6, lane = tid & 63;
    const int r15 = lane & 15, g4 = lane >> 4;
    unsigned short* ob = b ? ob1 : ob0;

    __shared__ __attribute__((aligned(16))) unsigned short Slds[32 * 128];
    __shared__ __attribute__((aligned(16))) unsigned short Ulds[32 * 64];
    __shared__ __attribute__((aligned(16))) unsigned short Uplds[32 * 64];

    f4v S[2][2];
#pragma unroll
    for (int i = 0; i < 2; i++)
#pragma unroll
        for (int j = 0; j < 2; j++) S[i][j] = (f4v){0,0,0,0};

    for (int c = 0; c < NC_; c++) {
        const size_t cbk = ((size_t)(b * 32 + h) * 32 + c);
        const size_t t0 = (size_t)b * T_ + (size_t)c * 64;

        // phase 0: stage S0 -> Slds (bf16 [v][dk], swizzled)
#pragma unroll
        for (int dkt = 0; dkt < 2; dkt++)
#pragma unroll
            for (int vt = 0; vt < 2; vt++) {
                int v = vt * 16 + r15;
                int dkb = ((wid * 2 + dkt) * 16 + g4 * 4) * 2;
                int sw = (v & 7) << 4;
                *(unsigned int*)((char*)Slds + v * 256 + ((dkb) ^ sw))     = pk2(S[dkt][vt][0], S[dkt][vt][1]);
                *(unsigned int*)((char*)Slds + v * 256 + ((dkb + 4) ^ sw)) = pk2(S[dkt][vt][2], S[dkt][vt][3]);
            }
        __syncthreads();

        // phase 1: P = Wmat @ S0 ; U = TbV - P -> Ulds, U' -> Uplds
        f4v P[2]; P[0] = (f4v){0,0,0,0}; P[1] = (f4v){0,0,0,0};
        s8v sf[4][2];
        const unsigned short* wp = Wg + cbk * 8192 + (size_t)(wid * 16 + r15) * 128;
#pragma unroll
        for (int ks = 0; ks < 4; ks++) {
            s8v aw = *(const s8v*)(wp + ks * 32 + g4 * 8);
#pragma unroll
            for (int vt = 0; vt < 2; vt++) {
                int v = vt * 16 + r15;
                sf[ks][vt] = *(const s8v*)((const char*)Slds + v * 256 + ((ks * 64 + g4 * 16) ^ ((v & 7) << 4)));
                P[vt] = __builtin_amdgcn_mfma_f32_16x16x32_bf16(aw, sf[ks][vt], P[vt], 0, 0, 0);
            }
        }
        float egr[4];
#pragma unroll
        for (int r = 0; r < 4; r++) egr[r] = expGr[cbk * 64 + wid * 16 + g4 * 4 + r];
#pragma unroll
        for (int vt = 0; vt < 2; vt++) {
            float uu[4], up[4];
#pragma unroll
            for (int r = 0; r < 4; r++) {
                int t = wid * 16 + g4 * 4 + r;
                unsigned short tv = tbv[(t0 + t) * VAL_DIM_ + h * 128 + vq * 32 + vt * 16 + r15];
                uu[r] = b2f(tv) - P[vt][r];
                up[r] = uu[r] * egr[r];
            }
            int v = vt * 16 + r15;
            int tb2 = (wid * 16 + g4 * 4) * 2;
            int sw = (v & 7) << 4;
            *(unsigned int*)((char*)Ulds  + v * 128 + ((tb2) ^ sw))     = pk2(uu[0], uu[1]);
            *(unsigned int*)((char*)Ulds  + v * 128 + ((tb2 + 4) ^ sw)) = pk2(uu[2], uu[3]);
            *(unsigned int*)((char*)Uplds + v * 128 + ((tb2) ^ sw))     = pk2(up[0], up[1]);
            *(unsigned int*)((char*)Uplds + v * 128 + ((tb2 + 4) ^ sw)) = pk2(up[2], up[3]);
        }
        __syncthreads();

        // phase 2: O = (e^G q) @ S0 + Ao @ U
        f4v O[2]; O[0] = (f4v){0,0,0,0}; O[1] = (f4v){0,0,0,0};
        float egi = expG[cbk * 64 + wid * 16 + r15];
        const unsigned short* qp = qn + ((t0 + wid * 16 + r15) * HK_ + hk) * DK_;
#pragma unroll
        for (int ks = 0; ks < 4; ks++) {
            s8v q0 = *(const s8v*)(qp + ks * 32 + g4 * 8);
            s8v qg;
#pragma unroll
            for (int e = 0; e < 8; e++) qg[e] = (short)f2b(b2f((unsigned short)q0[e]) * egi);
#pragma unroll
            for (int vt = 0; vt < 2; vt++)
                O[vt] = __builtin_amdgcn_mfma_f32_16x16x32_bf16(qg, sf[ks][vt], O[vt], 0, 0, 0);
        }
        const unsigned short* ap = Aog + cbk * 4096 + (size_t)(wid * 16 + r15) * 64;
#pragma unroll
        for (int ks = 0; ks < 2; ks++) {
            s8v aa = *(const s8v*)(ap + ks * 32 + g4 * 8);
#pragma unroll
            for (int vt = 0; vt < 2; vt++) {
                int v = vt * 16 + r15;
                s8v bu = *(const s8v*)((const char*)Ulds + v * 128 + ((ks * 64 + g4 * 16) ^ ((v & 7) << 4)));
                O[vt] = __builtin_amdgcn_mfma_f32_16x16x32_bf16(aa, bu, O[vt], 0, 0, 0);
            }
        }
#pragma unroll
        for (int vt = 0; vt < 2; vt++)
#pragma unroll
            for (int r = 0; r < 4; r++) {
                int t = c * 64 + wid * 16 + g4 * 4 + r;
                ob[(size_t)t * VAL_DIM_ + h * 128 + vq * 32 + vt * 16 + r15] = f2b(O[vt][r]);
            }

        // phase 3: S = gamma*S + knT @ U'
        float gam = expG[cbk * 64 + 63];
#pragma unroll
        for (int dkt = 0; dkt < 2; dkt++)
#pragma unroll
            for (int vt = 0; vt < 2; vt++) {
                S[dkt][vt][0] *= gam; S[dkt][vt][1] *= gam;
                S[dkt][vt][2] *= gam; S[dkt][vt][3] *= gam;
            }
        const unsigned short* kp = knT + ((size_t)(b * 16 + hk) * 128) * (size_t)T_;
#pragma unroll
        for (int ks = 0; ks < 2; ks++) {
            s8v bu[2];
#pragma unroll
            for (int vt = 0; vt < 2; vt++) {
                int v = vt * 16 + r15;
                bu[vt] = *(const s8v*)((const char*)Uplds + v * 128 + ((ks * 64 + g4 * 16) ^ ((v & 7) << 4)));
            }
#pragma unroll
            for (int dkt = 0; dkt < 2; dkt++) {
                s8v ak = *(const s8v*)(kp + (size_t)((wid * 2 + dkt) * 16 + r15) * T_ + (size_t)c * 64 + ks * 32 + g4 * 8);
#pragma unroll
                for (int vt = 0; vt < 2; vt++)
                    S[dkt][vt] = __builtin_amdgcn_mfma_f32_16x16x32_bf16(ak, bu[vt], S[dkt][vt], 0, 0, 0);
            }
        }
        __syncthreads();
    }
}

// ---------------- gated RMSNorm + silu(z) gate (in-place, bf16) ----------------
__global__ void norm_gate_k(unsigned short* __restrict__ o, const unsigned short* __restrict__ z,
                            const float* __restrict__ nw) {
    int bth = blockIdx.x;
    int d = threadIdx.x;
    float val = b2f(o[(size_t)bth * DV_ + d]);
    float ss = val * val;
#pragma unroll
    for (int m = 1; m < 64; m <<= 1) ss += __shfl_xor(ss, m);
    __shared__ float sred[2];
    if ((d & 63) == 0) sred[d >> 6] = ss;
    __syncthreads();
    float var = (sred[0] + sred[1]) * (1.f / 128.f);
    float zn = b2f(z[(size_t)bth * DV_ + d]);
    float on = val * rsqrtf(var + 1e-6f) * nw[d] * silu(zn);
    o[(size_t)bth * DV_ + d] = f2b(on);
}

// ---------------- launch ----------------
// ws regions (MB = 1<<20), total 194MB:
//  @0    (64MB): mixp | then Wmat[0:32) knT[32:48) obuf0[48:64)
//  @64M  (32MB): WqkvT | then Ao[0:16), kn[16:32) -> obuf1[16:32)
//  @96M  (16MB): WzT -> WoutT
//  @112M (16MB): xb -> qn
//  @128M (32MB): vv -> TbV (in place)
//  @160M (32MB): zb
//  @192M (2MB):  gbuf, bbuf, expG, expGr
extern "C" void kernel_launch(void* const* d_in, const int* in_sizes, int n_in,
                              void* d_out, int out_size, void* d_ws, size_t ws_size,
                              hipStream_t stream) {
    const float* x      = (const float*)d_in[0];
    const float* W_qkv  = (const float*)d_in[1];
    const float* W_z    = (const float*)d_in[2];
    const float* W_a    = (const float*)d_in[3];
    const float* W_b    = (const float*)d_in[4];
    const float* W_out  = (const float*)d_in[5];
    const float* conv_w = (const float*)d_in[6];
    const float* dt_bias= (const float*)d_in[7];
    const float* A_log  = (const float*)d_in[8];
    const float* norm_w = (const float*)d_in[9];

    char* w = (char*)d_ws;
    const size_t MBc = (size_t)1 << 20;
    unsigned short* mixp  = (unsigned short*)(w);
    unsigned short* Wmat  = (unsigned short*)(w);
    unsigned short* knT   = (unsigned short*)(w + 32 * MBc);
    unsigned short* obuf0 = (unsigned short*)(w + 48 * MBc);
    unsigned short* WqkvT = (unsigned short*)(w + 64 * MBc);
    unsigned short* Aog   = (unsigned short*)(w + 64 * MBc);
    unsigned short* kn    = (unsigned short*)(w + 80 * MBc);
    unsigned short* obuf1 = (unsigned short*)(w + 80 * MBc);
    unsigned short* WzT   = (unsigned short*)(w + 96 * MBc);
    unsigned short* WoutT = (unsigned short*)(w + 96 * MBc);
    unsigned short* xb    = (unsigned short*)(w + 112 * MBc);
    unsigned short* qn    = (unsigned short*)(w + 112 * MBc);
    unsigned short* vv    = (unsigned short*)(w + 128 * MBc);
    unsigned short* zb    = (unsigned short*)(w + 160 * MBc);
    float* gbuf  = (float*)(w + 192 * MBc);
    float* bbuf  = (float*)(w + 192 * MBc + 512 * 1024);
    float* expG  = (float*)(w + 192 * MBc + 1024 * 1024);
    float* expGr = (float*)(w + 192 * MBc + 1536 * 1024);

    cast_bf16_k<<<(BT_ * DIM_ / 8 + 255) / 256, 256, 0, stream>>>(x, xb, BT_ * DIM_ / 8);
    transpose_cast_k<<<dim3(CONV_DIM_ / 32, DIM_ / 32), 256, 0, stream>>>(W_qkv, WqkvT, DIM_, CONV_DIM_);
    transpose_cast_k<<<dim3(VAL_DIM_ / 32, DIM_ / 32), 256, 0, stream>>>(W_z, WzT, DIM_, VAL_DIM_);
    gemm_bt_k<1><<<dim3(CONV_DIM_ / 128, BT_ / 128), 256, 0, stream>>>(xb, WqkvT, mixp, BT_, CONV_DIM_, DIM_);
    gemm_bt_k<1><<<dim3(VAL_DIM_ / 128, BT_ / 128), 256, 0, stream>>>(xb, WzT, zb, BT_, VAL_DIM_, DIM_);
    transpose_cast_k<<<dim3(DIM_ / 32, VAL_DIM_ / 32), 256, 0, stream>>>(W_out, WoutT, VAL_DIM_, DIM_);
    ab_gbeta_k<<<BT_, 256, 0, stream>>>(x, W_a, W_b, dt_bias, A_log, gbuf, bbuf);
    conv_fused_k<<<dim3(BT_, CONV_DIM_ / 128), 128, 0, stream>>>(mixp, conv_w, qn, kn, vv);
    chunk_pre_k<<<dim3(NC_, HV_, B_), 256, 0, stream>>>(qn, kn, vv, gbuf, bbuf,
                                                        Wmat, Aog, knT, expG, expGr);
    chunk_scan_k<<<B_ * HV_ * 4, 256, 0, stream>>>(qn, knT, vv, Wmat, Aog, expG, expGr, obuf0, obuf1);
    norm_gate_k<<<2048 * HV_, 128, 0, stream>>>(obuf0, zb, norm_w);
    norm_gate_k<<<2048 * HV_, 128, 0, stream>>>(obuf1, zb + (size_t)2048 * VAL_DIM_, norm_w);
    gemm_bt_k<0><<<dim3(DIM_ / 128, 2048 / 128), 256, 0, stream>>>(obuf0, WoutT, d_out, 2048, DIM_, VAL_DIM_);
    gemm_bt_k<0><<<dim3(DIM_ / 128, 2048 / 128), 256, 0, stream>>>(obuf1, WoutT,
                                                                   (float*)d_out + (size_t)2048 * DIM_, 2048, DIM_, VAL_DIM_);
}

// Round 5
// 793.820 us; speedup vs baseline: 2.4902x; 1.2033x over previous
//
#include <hip/hip_runtime.h>
#include <hip/hip_bf16.h>
#include <cstdint>
#include <cstddef>

#define DIM_ 2048
#define HV_ 32
#define HK_ 16
#define DK_ 128
#define DV_ 128
#define KW_ 4
#define KEY_DIM_ 2048
#define VAL_DIM_ 4096
#define CONV_DIM_ 8192
#define B_ 2
#define T_ 2048
#define BT_ 4096
#define CH_ 64
#define NC_ (T_ / CH_)

typedef short s8v __attribute__((ext_vector_type(8)));
typedef float f4v __attribute__((ext_vector_type(4)));

__device__ __forceinline__ unsigned short f2b(float f) {
    union { float f; unsigned u; } c; c.f = f;
    unsigned u = c.u;
    return (unsigned short)((u + 0x7fffu + ((u >> 16) & 1u)) >> 16);
}
__device__ __forceinline__ float b2f(unsigned short s) {
    union { unsigned u; float f; } c; c.u = ((unsigned)s) << 16;
    return c.f;
}
__device__ __forceinline__ unsigned int pk2(float a, float b) {
    return (unsigned)f2b(a) | ((unsigned)f2b(b) << 16);
}
__device__ __forceinline__ float silu(float x) { return x / (1.f + expf(-x)); }

// ---------------- cast f32 -> bf16 ----------------
__global__ void cast_bf16_k(const float* __restrict__ in, unsigned short* __restrict__ out, int n8) {
    int i = blockIdx.x * blockDim.x + threadIdx.x;
    if (i >= n8) return;
    int base = i * 8;
    f4v a = *(const f4v*)(in + base);
    f4v b = *(const f4v*)(in + base + 4);
    s8v o;
    o[0] = (short)f2b(a[0]); o[1] = (short)f2b(a[1]); o[2] = (short)f2b(a[2]); o[3] = (short)f2b(a[3]);
    o[4] = (short)f2b(b[0]); o[5] = (short)f2b(b[1]); o[6] = (short)f2b(b[2]); o[7] = (short)f2b(b[3]);
    *(s8v*)(out + base) = o;
}

// ---------------- transpose + cast ----------------
__global__ void transpose_cast_k(const float* __restrict__ in, unsigned short* __restrict__ out,
                                 int R, int C) {
    __shared__ float tile[32][33];
    int c0 = blockIdx.x * 32, r0 = blockIdx.y * 32;
    int tx = threadIdx.x & 31, ty = threadIdx.x >> 5;
#pragma unroll
    for (int j = 0; j < 32; j += 8)
        tile[ty + j][tx] = in[(size_t)(r0 + ty + j) * C + c0 + tx];
    __syncthreads();
#pragma unroll
    for (int j = 0; j < 32; j += 8)
        out[(size_t)(c0 + ty + j) * R + r0 + tx] = f2b(tile[tx][ty + j]);
}

// ---------------- bf16 GEMM: C[M,N] = A[M,K] * BT[N,K]^T  (m97 + T1 XCD swizzle) ----------------
template <int OUT_BF16>
__global__ __launch_bounds__(256) void gemm_bt_k(const unsigned short* __restrict__ A,
                                                 const unsigned short* __restrict__ BT,
                                                 void* __restrict__ Cv,
                                                 int M, int N, int K) {
    __shared__ __attribute__((aligned(16))) unsigned short As[128 * 64];
    __shared__ __attribute__((aligned(16))) unsigned short Bs[128 * 64];
    const int tid = threadIdx.x;
    const int wid = tid >> 6, lane = tid & 63;
    const int wm = wid >> 1, wn = wid & 1;
    // XCD-aware bijective swizzle (grids here always have nwg % 8 == 0)
    int bid = blockIdx.x + gridDim.x * blockIdx.y;
    int cpx = (gridDim.x * gridDim.y) >> 3;
    int swz = (bid & 7) * cpx + (bid >> 3);
    const int m0 = (swz / gridDim.x) * 128, n0 = (swz % gridDim.x) * 128;

    f4v acc[4][4];
#pragma unroll
    for (int i = 0; i < 4; i++)
#pragma unroll
        for (int j = 0; j < 4; j++) acc[i][j] = (f4v){0.f, 0.f, 0.f, 0.f};

    const int rowA = tid >> 3;
    const int cb   = (tid & 7) << 4;

    for (int kt = 0; kt < K; kt += 64) {
#pragma unroll
        for (int i = 0; i < 4; i++) {
            int row = i * 32 + rowA;
            int scb = cb ^ ((row & 7) << 4);
            const unsigned short* ga = A  + (size_t)(m0 + row) * K + kt + (scb >> 1);
            const unsigned short* gb = BT + (size_t)(n0 + row) * K + kt + (scb >> 1);
            char* la = (char*)As + i * 4096 + (wid << 10);
            char* lb = (char*)Bs + i * 4096 + (wid << 10);
            __builtin_amdgcn_global_load_lds(
                (const __attribute__((address_space(1))) unsigned int*)ga,
                (__attribute__((address_space(3))) unsigned int*)la, 16, 0, 0);
            __builtin_amdgcn_global_load_lds(
                (const __attribute__((address_space(1))) unsigned int*)gb,
                (__attribute__((address_space(3))) unsigned int*)lb, 16, 0, 0);
        }
        __syncthreads();
#pragma unroll
        for (int kk = 0; kk < 2; kk++) {
            s8v af[4], bfr[4];
#pragma unroll
            for (int mi = 0; mi < 4; mi++) {
                int row = wm * 64 + mi * 16 + (lane & 15);
                int byteoff = (row << 7) + ((kk * 64 + ((lane >> 4) << 4)) ^ ((row & 7) << 4));
                af[mi] = *(const s8v*)((const char*)As + byteoff);
            }
#pragma unroll
            for (int ni = 0; ni < 4; ni++) {
                int row = wn * 64 + ni * 16 + (lane & 15);
                int byteoff = (row << 7) + ((kk * 64 + ((lane >> 4) << 4)) ^ ((row & 7) << 4));
                bfr[ni] = *(const s8v*)((const char*)Bs + byteoff);
            }
#pragma unroll
            for (int mi = 0; mi < 4; mi++)
#pragma unroll
                for (int ni = 0; ni < 4; ni++)
                    acc[mi][ni] = __builtin_amdgcn_mfma_f32_16x16x32_bf16(
                        af[mi], bfr[ni], acc[mi][ni], 0, 0, 0);
        }
        __syncthreads();
    }
#pragma unroll
    for (int mi = 0; mi < 4; mi++) {
#pragma unroll
        for (int ni = 0; ni < 4; ni++) {
            int row = m0 + wm * 64 + mi * 16 + ((lane >> 4) << 2);
            int col = n0 + wn * 64 + ni * 16 + (lane & 15);
#pragma unroll
            for (int r = 0; r < 4; r++) {
                float v = acc[mi][ni][r];
                if (OUT_BF16)
                    ((unsigned short*)Cv)[(size_t)(row + r) * N + col] = f2b(v);
                else
                    ((float*)Cv)[(size_t)(row + r) * N + col] = v;
            }
        }
    }
}

// ---------------- a,b GEMM (exact f32) + g/beta: 16 rows/block ----------------
__global__ __launch_bounds__(256) void ab_gbeta_k(const float* __restrict__ x,
                                                  const float* __restrict__ Wa,
                                                  const float* __restrict__ Wb,
                                                  const float* __restrict__ dt_bias,
                                                  const float* __restrict__ A_log,
                                                  float* __restrict__ g, float* __restrict__ beta) {
    __shared__ float xr0[16 * 513];
    const int tid = threadIdx.x;
    const int r = tid & 15, cc = tid >> 4;
    const int row0 = blockIdx.x * 16;
    float a0 = 0.f, a1 = 0.f, b0 = 0.f, b1 = 0.f;
    for (int kc = 0; kc < 2048; kc += 512) {
#pragma unroll
        for (int q = 0; q < 8; q++) {
            int f = q * 256 + tid;
            int rw = f >> 7, cl = (f & 127) << 2;
            *(f4v*)&xr0[rw * 513 + cl] = *(const f4v*)(x + (size_t)(row0 + rw) * 2048 + kc + cl);
        }
        __syncthreads();
#pragma unroll 8
        for (int k = 0; k < 512; k++) {
            float xv = xr0[r * 513 + k];
            size_t kk = (size_t)(kc + k) * 32;
            a0 += xv * Wa[kk + cc];
            a1 += xv * Wa[kk + cc + 16];
            b0 += xv * Wb[kk + cc];
            b1 += xv * Wb[kk + cc + 16];
        }
        __syncthreads();
    }
    int row = row0 + r;
    float av0 = a0 + dt_bias[cc], av1 = a1 + dt_bias[cc + 16];
    float sp0 = (av0 > 20.f) ? av0 : log1pf(expf(av0));
    float sp1 = (av1 > 20.f) ? av1 : log1pf(expf(av1));
    g[(size_t)row * 32 + cc]      = -expf(A_log[cc]) * sp0;
    g[(size_t)row * 32 + cc + 16] = -expf(A_log[cc + 16]) * sp1;
    beta[(size_t)row * 32 + cc]      = 1.f / (1.f + expf(-b0));
    beta[(size_t)row * 32 + cc + 16] = 1.f / (1.f + expf(-b1));
}

// ---------------- conv + silu + l2norm + split (uint-vectorized, wave=group) ----------------
__global__ __launch_bounds__(256) void conv_fused_k(const unsigned short* __restrict__ mixp,
                                                    const float* __restrict__ convw,
                                                    unsigned short* __restrict__ qn,
                                                    unsigned short* __restrict__ kn,
                                                    unsigned short* __restrict__ vv) {
    int btid = blockIdx.x;
    int t = btid & (T_ - 1);
    int c = (blockIdx.y << 9) + (threadIdx.x << 1);   // channel pair c, c+1
    const unsigned short* base = mixp + (size_t)btid * CONV_DIM_ + c;
    unsigned m3 = *(const unsigned*)(base);
    unsigned m2 = (t >= 1) ? *(const unsigned*)(base - CONV_DIM_) : 0u;
    unsigned m1 = (t >= 2) ? *(const unsigned*)(base - 2 * CONV_DIM_) : 0u;
    unsigned m0 = (t >= 3) ? *(const unsigned*)(base - 3 * CONV_DIM_) : 0u;
    f4v w0 = *(const f4v*)(convw + (size_t)c * 4);
    f4v w1 = *(const f4v*)(convw + (size_t)c * 4 + 4);
    float v0 = b2f((unsigned short)(m3 & 0xffff)) * w0[3] + b2f((unsigned short)(m2 & 0xffff)) * w0[2]
             + b2f((unsigned short)(m1 & 0xffff)) * w0[1] + b2f((unsigned short)(m0 & 0xffff)) * w0[0];
    float v1 = b2f((unsigned short)(m3 >> 16)) * w1[3] + b2f((unsigned short)(m2 >> 16)) * w1[2]
             + b2f((unsigned short)(m1 >> 16)) * w1[1] + b2f((unsigned short)(m0 >> 16)) * w1[0];
    v0 = silu(v0); v1 = silu(v1);
    if (c < 2 * KEY_DIM_) {
        float ss = v0 * v0 + v1 * v1;
#pragma unroll
        for (int m = 1; m < 64; m <<= 1) ss += __shfl_xor(ss, m);   // 64 lanes = 128 channels = 1 group
        float scale = rsqrtf(ss + 1e-6f);
        int head = (c >> 7) & 15, d = c & 127;
        if (c < KEY_DIM_) {
            scale *= 0.08838834764831845f; // DK^-0.5
            *(unsigned*)(qn + ((size_t)btid * HK_ + head) * DK_ + d) = pk2(v0 * scale, v1 * scale);
        } else {
            *(unsigned*)(kn + ((size_t)btid * HK_ + head) * DK_ + d) = pk2(v0 * scale, v1 * scale);
        }
    } else {
        *(unsigned*)(vv + (size_t)btid * VAL_DIM_ + (c - 2 * KEY_DIM_)) = pk2(v0, v1);
    }
}

// ================= chunked delta rule: parallel precompute =================
__global__ __launch_bounds__(256) void chunk_pre_k(
    const unsigned short* __restrict__ qn, const unsigned short* __restrict__ kn,
    unsigned short* __restrict__ vv,
    const float* __restrict__ g, const float* __restrict__ beta,
    unsigned short* __restrict__ Wg, unsigned short* __restrict__ Aog,
    unsigned short* __restrict__ knT, float* __restrict__ expG, float* __restrict__ expGr)
{
    const int c = blockIdx.x, h = blockIdx.y, b = blockIdx.z;
    const int hk = h >> 1;
    const int tid = threadIdx.x, wid = tid >> 6, lane = tid & 63;
    const int r15 = lane & 15, g4 = lane >> 4;

    __shared__ __attribute__((aligned(16))) unsigned short Klds[64 * 128];
    __shared__ __attribute__((aligned(16))) unsigned short Xlds[128 * 64];
    __shared__ float AT[64][68];
    __shared__ float STmp[16][17];
    __shared__ float Gl[64], Bl[64], EG[64];

    const size_t t0 = (size_t)b * T_ + (size_t)c * 64;
    const size_t cbk = ((size_t)(b * 32 + h) * 32 + c);

    // phase a: stage K,Q swizzled (full 256B rows)
#pragma unroll
    for (int p = 0; p < 4; p++) {
        int row = p * 16 + (tid >> 4);
        int colB = (tid & 15) << 4;
        int sw = colB ^ ((row & 7) << 4);
        s8v kv = *(const s8v*)(kn + ((t0 + row) * HK_ + hk) * DK_ + (colB >> 1));
        *(s8v*)((char*)Klds + row * 256 + sw) = kv;
        s8v qv = *(const s8v*)(qn + ((t0 + row) * HK_ + hk) * DK_ + (colB >> 1));
        *(s8v*)((char*)Xlds + row * 256 + sw) = qv;
    }
    if (tid < 64) {
        Gl[tid] = g[(t0 + tid) * HV_ + h];
        Bl[tid] = beta[(t0 + tid) * HV_ + h];
    }
    __syncthreads();
    if (tid == 0) {
        float s = 0.f;
        for (int i = 0; i < 64; i++) { s += Gl[i]; Gl[i] = s; }
    }
    __syncthreads();
    if (tid < 64) {
        float Gi = Gl[tid], Gn = Gl[63];
        float e1 = expf(Gi), e2 = expf(Gn - Gi);
        EG[tid] = e1;
        expG[cbk * 64 + tid] = e1;
        expGr[cbk * 64 + tid] = e2;
    }
    __syncthreads();

    // phase b: KK = K K^T, QK = Q K^T
    f4v kkv[4], qkv[4];
#pragma unroll
    for (int jt = 0; jt < 4; jt++) { kkv[jt] = (f4v){0,0,0,0}; qkv[jt] = (f4v){0,0,0,0}; }
    const int arow = wid * 16 + r15;
#pragma unroll
    for (int ks = 0; ks < 4; ks++) {
        int abyte = arow * 256 + ((ks * 64 + (g4 << 4)) ^ ((arow & 7) << 4));
        s8v ak = *(const s8v*)((const char*)Klds + abyte);
        s8v aq = *(const s8v*)((const char*)Xlds + abyte);
#pragma unroll
        for (int jt = 0; jt < 4; jt++) {
            int jrow = jt * 16 + r15;
            int bbyte = jrow * 256 + ((ks * 64 + (g4 << 4)) ^ ((jrow & 7) << 4));
            s8v bk = *(const s8v*)((const char*)Klds + bbyte);
            kkv[jt] = __builtin_amdgcn_mfma_f32_16x16x32_bf16(ak, bk, kkv[jt], 0, 0, 0);
            qkv[jt] = __builtin_amdgcn_mfma_f32_16x16x32_bf16(aq, bk, qkv[jt], 0, 0, 0);
        }
    }
    // A build (strictly lower) + Ao write (j<=i)
#pragma unroll
    for (int jt = 0; jt < 4; jt++) {
#pragma unroll
        for (int r = 0; r < 4; r++) {
            int i = wid * 16 + g4 * 4 + r;
            int j = jt * 16 + r15;
            float em = expf(fminf(Gl[i] - Gl[j], 0.f));
            AT[i][j] = (j < i) ? Bl[i] * em * kkv[jt][r] : 0.f;
            float ao = (j <= i) ? em * qkv[jt][r] : 0.f;
            Aog[cbk * 4096 + i * 64 + j] = f2b(ao);
        }
    }
    __syncthreads();

    // phase c1: V load+scale -> Xlds ; knT write (even h) — all 256 threads
    for (int u = tid; u < 1024; u += 256) {
        int row = u >> 4, v0i = (u & 15) << 3;
        s8v vx = *(const s8v*)(vv + (t0 + row) * VAL_DIM_ + h * 128 + v0i);
        float bt = Bl[row];
#pragma unroll
        for (int e = 0; e < 8; e++) {
            int v = v0i + e;
            *(unsigned short*)((char*)Xlds + v * 128 + ((row * 2) ^ ((v & 7) << 4))) =
                f2b(b2f((unsigned short)vx[e]) * bt);
        }
    }
    if ((h & 1) == 0) {
        int dk = tid & 127, th = (tid >> 7) << 5;
        size_t basek = ((size_t)(b * 16 + hk) * 128 + dk) * (size_t)T_ + (size_t)c * 64 + th;
        for (int t2 = 0; t2 < 32; t2++) {
            int tt = th + t2;
            knT[basek + t2] = *(const unsigned short*)((const char*)Klds + tt * 256 + ((dk * 2) ^ ((tt & 7) << 4)));
        }
    }
    __syncthreads();

    // phase c2: blocked trisolve — diag 16x16 inverses, wave wid owns block wid
    if (lane < 16) {
        int r0 = wid * 16, col = lane;
#pragma unroll
        for (int i = 0; i < 16; i++) {
            float s = 0.f;
            for (int j = 0; j < i; j++) s += AT[r0 + i][r0 + j] * AT[r0 + j][r0 + col];
            AT[r0 + i][r0 + col] = ((col == i) ? 1.f : 0.f) - s;
        }
    }
    __syncthreads();

    // phase c3: off-diagonal blocks X_IJ = -X_II (sum_{K=J..I-1} A_IK X_KJ), ascending J
    {
        int ii = tid >> 4, jj = tid & 15;
        for (int I = 1; I < 4; I++)
            for (int J = 0; J < I; J++) {
                float s = 0.f;
                for (int K = J; K < I; K++) {
#pragma unroll
                    for (int m = 0; m < 16; m++)
                        s += AT[16 * I + ii][16 * K + m] * AT[16 * K + m][16 * J + jj];
                }
                STmp[ii][jj] = s;
                __syncthreads();
                float y = 0.f;
#pragma unroll
                for (int m = 0; m < 16; m++) y += AT[16 * I + ii][16 * I + m] * STmp[m][jj];
                __syncthreads();
                AT[16 * I + ii][16 * J + jj] = -y;
                __syncthreads();
            }
    }

    // phase d: TbV = T @ (beta V)  -> vv in place
    f4v tb[8];
#pragma unroll
    for (int vt = 0; vt < 8; vt++) tb[vt] = (f4v){0,0,0,0};
#pragma unroll
    for (int ks = 0; ks < 2; ks++) {
        s8v ta;
#pragma unroll
        for (int e = 0; e < 8; e++) ta[e] = (short)f2b(AT[arow][ks * 32 + g4 * 8 + e]);
#pragma unroll
        for (int vt = 0; vt < 8; vt++) {
            int v = vt * 16 + r15;
            int bbyte = v * 128 + ((ks * 64 + (g4 << 4)) ^ ((v & 7) << 4));
            s8v bv = *(const s8v*)((const char*)Xlds + bbyte);
            tb[vt] = __builtin_amdgcn_mfma_f32_16x16x32_bf16(ta, bv, tb[vt], 0, 0, 0);
        }
    }
#pragma unroll
    for (int vt = 0; vt < 8; vt++)
#pragma unroll
        for (int r = 0; r < 4; r++) {
            int i = wid * 16 + g4 * 4 + r, v = vt * 16 + r15;
            vv[(t0 + i) * VAL_DIM_ + h * 128 + v] = f2b(tb[vt][r]);
        }
    __syncthreads();

    // phase e: KwT[dk][t] = beta_t e^{G_t} K[t][dk]  (into Xlds)
    if (tid < 128) {
        int dk = tid;
        for (int t = 0; t < 64; t++) {
            float kv = b2f(*(const unsigned short*)((const char*)Klds + t * 256 + ((dk * 2) ^ ((t & 7) << 4))));
            *(unsigned short*)((char*)Xlds + dk * 128 + ((t * 2) ^ ((dk & 7) << 4))) =
                f2b(kv * Bl[t] * EG[t]);
        }
    }
    __syncthreads();

    // phase f: Wmat = T @ Kw
    f4v wm[8];
#pragma unroll
    for (int dt = 0; dt < 8; dt++) wm[dt] = (f4v){0,0,0,0};
#pragma unroll
    for (int ks = 0; ks < 2; ks++) {
        s8v ta;
#pragma unroll
        for (int e = 0; e < 8; e++) ta[e] = (short)f2b(AT[arow][ks * 32 + g4 * 8 + e]);
#pragma unroll
        for (int dt = 0; dt < 8; dt++) {
            int dkr = dt * 16 + r15;
            int bbyte = dkr * 128 + ((ks * 64 + (g4 << 4)) ^ ((dkr & 7) << 4));
            s8v bw = *(const s8v*)((const char*)Xlds + bbyte);
            wm[dt] = __builtin_amdgcn_mfma_f32_16x16x32_bf16(ta, bw, wm[dt], 0, 0, 0);
        }
    }
#pragma unroll
    for (int dt = 0; dt < 8; dt++)
#pragma unroll
        for (int r = 0; r < 4; r++) {
            int i = wid * 16 + g4 * 4 + r, dk = dt * 16 + r15;
            Wg[cbk * 8192 + i * 128 + dk] = f2b(wm[dt][r]);
        }
}

// ================= chunked delta rule: sequential scan =================
__global__ __launch_bounds__(256) void chunk_scan_k(
    const unsigned short* __restrict__ qn, const unsigned short* __restrict__ knT,
    const unsigned short* __restrict__ tbv,
    const unsigned short* __restrict__ Wg, const unsigned short* __restrict__ Aog,
    const float* __restrict__ expG, const float* __restrict__ expGr,
    unsigned short* __restrict__ ob)
{
    const int bx = blockIdx.x;
    const int vq = bx & 3, h = (bx >> 2) & 31, b = bx >> 7;
    const int hk = h >> 1;
    const int tid = threadIdx.x, wid = tid >> 6, lane = tid & 63;
    const int r15 = lane & 15, g4 = lane >> 4;

    __shared__ __attribute__((aligned(16))) unsigned short Slds[32 * 128];
    __shared__ __attribute__((aligned(16))) unsigned short Ulds[32 * 64];
    __shared__ __attribute__((aligned(16))) unsigned short Uplds[32 * 64];

    f4v S[2][2];
#pragma unroll
    for (int i = 0; i < 2; i++)
#pragma unroll
        for (int j = 0; j < 2; j++) S[i][j] = (f4v){0,0,0,0};

    for (int c = 0; c < NC_; c++) {
        const size_t cbk = ((size_t)(b * 32 + h) * 32 + c);
        const size_t t0 = (size_t)b * T_ + (size_t)c * 64;

        // phase 0: stage S0 -> Slds (bf16 [v][dk], swizzled)
#pragma unroll
        for (int dkt = 0; dkt < 2; dkt++)
#pragma unroll
            for (int vt = 0; vt < 2; vt++) {
                int v = vt * 16 + r15;
                int dkb = ((wid * 2 + dkt) * 16 + g4 * 4) * 2;
                int sw = (v & 7) << 4;
                *(unsigned int*)((char*)Slds + v * 256 + ((dkb) ^ sw))     = pk2(S[dkt][vt][0], S[dkt][vt][1]);
                *(unsigned int*)((char*)Slds + v * 256 + ((dkb + 4) ^ sw)) = pk2(S[dkt][vt][2], S[dkt][vt][3]);
            }
        __syncthreads();

        // phase 1: P = Wmat @ S0 ; U = TbV - P -> Ulds, U' -> Uplds
        f4v P[2]; P[0] = (f4v){0,0,0,0}; P[1] = (f4v){0,0,0,0};
        s8v sf[4][2];
        const unsigned short* wp = Wg + cbk * 8192 + (size_t)(wid * 16 + r15) * 128;
#pragma unroll
        for (int ks = 0; ks < 4; ks++) {
            s8v aw = *(const s8v*)(wp + ks * 32 + g4 * 8);
#pragma unroll
            for (int vt = 0; vt < 2; vt++) {
                int v = vt * 16 + r15;
                sf[ks][vt] = *(const s8v*)((const char*)Slds + v * 256 + ((ks * 64 + g4 * 16) ^ ((v & 7) << 4)));
                P[vt] = __builtin_amdgcn_mfma_f32_16x16x32_bf16(aw, sf[ks][vt], P[vt], 0, 0, 0);
            }
        }
        float egr[4];
#pragma unroll
        for (int r = 0; r < 4; r++) egr[r] = expGr[cbk * 64 + wid * 16 + g4 * 4 + r];
#pragma unroll
        for (int vt = 0; vt < 2; vt++) {
            float uu[4], up[4];
#pragma unroll
            for (int r = 0; r < 4; r++) {
                int t = wid * 16 + g4 * 4 + r;
                unsigned short tv = tbv[(t0 + t) * VAL_DIM_ + h * 128 + vq * 32 + vt * 16 + r15];
                uu[r] = b2f(tv) - P[vt][r];
                up[r] = uu[r] * egr[r];
            }
            int v = vt * 16 + r15;
            int tb2 = (wid * 16 + g4 * 4) * 2;
            int sw = (v & 7) << 4;
            *(unsigned int*)((char*)Ulds  + v * 128 + ((tb2) ^ sw))     = pk2(uu[0], uu[1]);
            *(unsigned int*)((char*)Ulds  + v * 128 + ((tb2 + 4) ^ sw)) = pk2(uu[2], uu[3]);
            *(unsigned int*)((char*)Uplds + v * 128 + ((tb2) ^ sw))     = pk2(up[0], up[1]);
            *(unsigned int*)((char*)Uplds + v * 128 + ((tb2 + 4) ^ sw)) = pk2(up[2], up[3]);
        }
        __syncthreads();

        // phase 2: O = (e^G q) @ S0 + Ao @ U
        f4v O[2]; O[0] = (f4v){0,0,0,0}; O[1] = (f4v){0,0,0,0};
        float egi = expG[cbk * 64 + wid * 16 + r15];
        const unsigned short* qp = qn + ((t0 + wid * 16 + r15) * HK_ + hk) * DK_;
#pragma unroll
        for (int ks = 0; ks < 4; ks++) {
            s8v q0 = *(const s8v*)(qp + ks * 32 + g4 * 8);
            s8v qg;
#pragma unroll
            for (int e = 0; e < 8; e++) qg[e] = (short)f2b(b2f((unsigned short)q0[e]) * egi);
#pragma unroll
            for (int vt = 0; vt < 2; vt++)
                O[vt] = __builtin_amdgcn_mfma_f32_16x16x32_bf16(qg, sf[ks][vt], O[vt], 0, 0, 0);
        }
        const unsigned short* ap = Aog + cbk * 4096 + (size_t)(wid * 16 + r15) * 64;
#pragma unroll
        for (int ks = 0; ks < 2; ks++) {
            s8v aa = *(const s8v*)(ap + ks * 32 + g4 * 8);
#pragma unroll
            for (int vt = 0; vt < 2; vt++) {
                int v = vt * 16 + r15;
                s8v bu = *(const s8v*)((const char*)Ulds + v * 128 + ((ks * 64 + g4 * 16) ^ ((v & 7) << 4)));
                O[vt] = __builtin_amdgcn_mfma_f32_16x16x32_bf16(aa, bu, O[vt], 0, 0, 0);
            }
        }
#pragma unroll
        for (int vt = 0; vt < 2; vt++)
#pragma unroll
            for (int r = 0; r < 4; r++) {
                int t = c * 64 + wid * 16 + g4 * 4 + r;
                ob[((size_t)b * T_ + t) * VAL_DIM_ + h * 128 + vq * 32 + vt * 16 + r15] = f2b(O[vt][r]);
            }

        // phase 3: S = gamma*S + knT @ U'
        float gam = expG[cbk * 64 + 63];
#pragma unroll
        for (int dkt = 0; dkt < 2; dkt++)
#pragma unroll
            for (int vt = 0; vt < 2; vt++) {
                S[dkt][vt][0] *= gam; S[dkt][vt][1] *= gam;
                S[dkt][vt][2] *= gam; S[dkt][vt][3] *= gam;
            }
        const unsigned short* kp = knT + ((size_t)(b * 16 + hk) * 128) * (size_t)T_;
#pragma unroll
        for (int ks = 0; ks < 2; ks++) {
            s8v bu[2];
#pragma unroll
            for (int vt = 0; vt < 2; vt++) {
                int v = vt * 16 + r15;
                bu[vt] = *(const s8v*)((const char*)Uplds + v * 128 + ((ks * 64 + g4 * 16) ^ ((v & 7) << 4)));
            }
#pragma unroll
            for (int dkt = 0; dkt < 2; dkt++) {
                s8v ak = *(const s8v*)(kp + (size_t)((wid * 2 + dkt) * 16 + r15) * T_ + (size_t)c * 64 + ks * 32 + g4 * 8);
#pragma unroll
                for (int vt = 0; vt < 2; vt++)
                    S[dkt][vt] = __builtin_amdgcn_mfma_f32_16x16x32_bf16(ak, bu[vt], S[dkt][vt], 0, 0, 0);
            }
        }
        __syncthreads();
    }
}

// ---------------- gated RMSNorm + silu(z) gate: wave-per-head, uint loads ----------------
__global__ __launch_bounds__(256) void norm_gate_k(unsigned short* __restrict__ o,
                                                   const unsigned short* __restrict__ z,
                                                   const float* __restrict__ nw) {
    int lane = threadIdx.x & 63;
    size_t bh = (size_t)blockIdx.x * 4 + (threadIdx.x >> 6);
    unsigned ov = *(unsigned*)(o + bh * 128 + lane * 2);
    float v0 = b2f((unsigned short)(ov & 0xffff)), v1 = b2f((unsigned short)(ov >> 16));
    float ss = v0 * v0 + v1 * v1;
#pragma unroll
    for (int m = 1; m < 64; m <<= 1) ss += __shfl_xor(ss, m);
    float rr = rsqrtf(ss * (1.f / 128.f) + 1e-6f);
    unsigned zv = *(const unsigned*)(z + bh * 128 + lane * 2);
    float z0 = b2f((unsigned short)(zv & 0xffff)), z1 = b2f((unsigned short)(zv >> 16));
    float o0 = v0 * rr * nw[lane * 2]     * silu(z0);
    float o1 = v1 * rr * nw[lane * 2 + 1] * silu(z1);
    *(unsigned*)(o + bh * 128 + lane * 2) = pk2(o0, o1);
}

// ---------------- launch ----------------
// ws regions (MB = 1<<20), total ~194MB:
//  @0-64:   mixp | then Wmat[0:32) knT[32:48) Aog[48:64)
//  @64-96:  WqkvT | kn@[80:96) (conv->pre) | obuf (contiguous 32MB, scan->norm->gemm)
//  @96-112: WzT -> WoutT
//  @112-128: xb -> qn
//  @128-160: vv -> TbV (in place)
//  @160-192: zb
//  @192+:   gbuf, bbuf, expG, expGr
extern "C" void kernel_launch(void* const* d_in, const int* in_sizes, int n_in,
                              void* d_out, int out_size, void* d_ws, size_t ws_size,
                              hipStream_t stream) {
    const float* x      = (const float*)d_in[0];
    const float* W_qkv  = (const float*)d_in[1];
    const float* W_z    = (const float*)d_in[2];
    const float* W_a    = (const float*)d_in[3];
    const float* W_b    = (const float*)d_in[4];
    const float* W_out  = (const float*)d_in[5];
    const float* conv_w = (const float*)d_in[6];
    const float* dt_bias= (const float*)d_in[7];
    const float* A_log  = (const float*)d_in[8];
    const float* norm_w = (const float*)d_in[9];

    char* w = (char*)d_ws;
    const size_t MBc = (size_t)1 << 20;
    unsigned short* mixp  = (unsigned short*)(w);
    unsigned short* Wmat  = (unsigned short*)(w);
    unsigned short* knT   = (unsigned short*)(w + 32 * MBc);
    unsigned short* Aog   = (unsigned short*)(w + 48 * MBc);
    unsigned short* WqkvT = (unsigned short*)(w + 64 * MBc);
    unsigned short* obuf  = (unsigned short*)(w + 64 * MBc);
    unsigned short* kn    = (unsigned short*)(w + 80 * MBc);
    unsigned short* WzT   = (unsigned short*)(w + 96 * MBc);
    unsigned short* WoutT = (unsigned short*)(w + 96 * MBc);
    unsigned short* xb    = (unsigned short*)(w + 112 * MBc);
    unsigned short* qn    = (unsigned short*)(w + 112 * MBc);
    unsigned short* vv    = (unsigned short*)(w + 128 * MBc);
    unsigned short* zb    = (unsigned short*)(w + 160 * MBc);
    float* gbuf  = (float*)(w + 192 * MBc);
    float* bbuf  = (float*)(w + 192 * MBc + 512 * 1024);
    float* expG  = (float*)(w + 192 * MBc + 1024 * 1024);
    float* expGr = (float*)(w + 192 * MBc + 1536 * 1024);

    cast_bf16_k<<<(BT_ * DIM_ / 8 + 255) / 256, 256, 0, stream>>>(x, xb, BT_ * DIM_ / 8);
    transpose_cast_k<<<dim3(CONV_DIM_ / 32, DIM_ / 32), 256, 0, stream>>>(W_qkv, WqkvT, DIM_, CONV_DIM_);
    transpose_cast_k<<<dim3(VAL_DIM_ / 32, DIM_ / 32), 256, 0, stream>>>(W_z, WzT, DIM_, VAL_DIM_);
    gemm_bt_k<1><<<dim3(CONV_DIM_ / 128, BT_ / 128), 256, 0, stream>>>(xb, WqkvT, mixp, BT_, CONV_DIM_, DIM_);
    gemm_bt_k<1><<<dim3(VAL_DIM_ / 128, BT_ / 128), 256, 0, stream>>>(xb, WzT, zb, BT_, VAL_DIM_, DIM_);
    transpose_cast_k<<<dim3(DIM_ / 32, VAL_DIM_ / 32), 256, 0, stream>>>(W_out, WoutT, VAL_DIM_, DIM_);
    ab_gbeta_k<<<BT_ / 16, 256, 0, stream>>>(x, W_a, W_b, dt_bias, A_log, gbuf, bbuf);
    conv_fused_k<<<dim3(BT_, CONV_DIM_ / 512), 256, 0, stream>>>(mixp, conv_w, qn, kn, vv);
    chunk_pre_k<<<dim3(NC_, HV_, B_), 256, 0, stream>>>(qn, kn, vv, gbuf, bbuf,
                                                        Wmat, Aog, knT, expG, expGr);
    chunk_scan_k<<<B_ * HV_ * 4, 256, 0, stream>>>(qn, knT, vv, Wmat, Aog, expG, expGr, obuf);
    norm_gate_k<<<BT_ * HV_ / 4, 256, 0, stream>>>(obuf, zb, norm_w);
    gemm_bt_k<0><<<dim3(DIM_ / 128, BT_ / 128), 256, 0, stream>>>(obuf, WoutT, d_out, BT_, DIM_, VAL_DIM_);
}

// Round 6
// 754.167 us; speedup vs baseline: 2.6212x; 1.0526x over previous
//
#include <hip/hip_runtime.h>
#include <hip/hip_bf16.h>
#include <cstdint>
#include <cstddef>

#define DIM_ 2048
#define HV_ 32
#define HK_ 16
#define DK_ 128
#define DV_ 128
#define KW_ 4
#define KEY_DIM_ 2048
#define VAL_DIM_ 4096
#define CONV_DIM_ 8192
#define B_ 2
#define T_ 2048
#define BT_ 4096
#define CH_ 64
#define NC_ (T_ / CH_)

typedef short s8v __attribute__((ext_vector_type(8)));
typedef float f4v __attribute__((ext_vector_type(4)));

__device__ __forceinline__ unsigned short f2b(float f) {
    union { float f; unsigned u; } c; c.f = f;
    unsigned u = c.u;
    return (unsigned short)((u + 0x7fffu + ((u >> 16) & 1u)) >> 16);
}
__device__ __forceinline__ float b2f(unsigned short s) {
    union { unsigned u; float f; } c; c.u = ((unsigned)s) << 16;
    return c.f;
}
__device__ __forceinline__ unsigned int pk2(float a, float b) {
    return (unsigned)f2b(a) | ((unsigned)f2b(b) << 16);
}
__device__ __forceinline__ float silu(float x) { return x / (1.f + expf(-x)); }

// ---------------- cast f32 -> bf16 ----------------
__global__ void cast_bf16_k(const float* __restrict__ in, unsigned short* __restrict__ out, int n8) {
    int i = blockIdx.x * blockDim.x + threadIdx.x;
    if (i >= n8) return;
    int base = i * 8;
    f4v a = *(const f4v*)(in + base);
    f4v b = *(const f4v*)(in + base + 4);
    s8v o;
    o[0] = (short)f2b(a[0]); o[1] = (short)f2b(a[1]); o[2] = (short)f2b(a[2]); o[3] = (short)f2b(a[3]);
    o[4] = (short)f2b(b[0]); o[5] = (short)f2b(b[1]); o[6] = (short)f2b(b[2]); o[7] = (short)f2b(b[3]);
    *(s8v*)(out + base) = o;
}

// ---------------- transpose + cast ----------------
__global__ void transpose_cast_k(const float* __restrict__ in, unsigned short* __restrict__ out,
                                 int R, int C) {
    __shared__ float tile[32][33];
    int c0 = blockIdx.x * 32, r0 = blockIdx.y * 32;
    int tx = threadIdx.x & 31, ty = threadIdx.x >> 5;
#pragma unroll
    for (int j = 0; j < 32; j += 8)
        tile[ty + j][tx] = in[(size_t)(r0 + ty + j) * C + c0 + tx];
    __syncthreads();
#pragma unroll
    for (int j = 0; j < 32; j += 8)
        out[(size_t)(c0 + ty + j) * R + r0 + tx] = f2b(tile[tx][ty + j]);
}

// ---------------- bf16 GEMM: C[M,N] = A[M,K] * BT[N,K]^T  (m97; NO xcd swizzle) ----------------
// R5 lesson: per-XCD chunked swizzle made each XCD stream all of B through its
// private L2 (FETCH 141->500MB, +25us). Default dispatch order is better here.
template <int OUT_BF16>
__global__ __launch_bounds__(256) void gemm_bt_k(const unsigned short* __restrict__ A,
                                                 const unsigned short* __restrict__ BT,
                                                 void* __restrict__ Cv,
                                                 int M, int N, int K) {
    __shared__ __attribute__((aligned(16))) unsigned short As[128 * 64];
    __shared__ __attribute__((aligned(16))) unsigned short Bs[128 * 64];
    const int tid = threadIdx.x;
    const int wid = tid >> 6, lane = tid & 63;
    const int wm = wid >> 1, wn = wid & 1;
    const int m0 = blockIdx.y * 128, n0 = blockIdx.x * 128;

    f4v acc[4][4];
#pragma unroll
    for (int i = 0; i < 4; i++)
#pragma unroll
        for (int j = 0; j < 4; j++) acc[i][j] = (f4v){0.f, 0.f, 0.f, 0.f};

    const int rowA = tid >> 3;
    const int cb   = (tid & 7) << 4;

    for (int kt = 0; kt < K; kt += 64) {
#pragma unroll
        for (int i = 0; i < 4; i++) {
            int row = i * 32 + rowA;
            int scb = cb ^ ((row & 7) << 4);
            const unsigned short* ga = A  + (size_t)(m0 + row) * K + kt + (scb >> 1);
            const unsigned short* gb = BT + (size_t)(n0 + row) * K + kt + (scb >> 1);
            char* la = (char*)As + i * 4096 + (wid << 10);
            char* lb = (char*)Bs + i * 4096 + (wid << 10);
            __builtin_amdgcn_global_load_lds(
                (const __attribute__((address_space(1))) unsigned int*)ga,
                (__attribute__((address_space(3))) unsigned int*)la, 16, 0, 0);
            __builtin_amdgcn_global_load_lds(
                (const __attribute__((address_space(1))) unsigned int*)gb,
                (__attribute__((address_space(3))) unsigned int*)lb, 16, 0, 0);
        }
        __syncthreads();
#pragma unroll
        for (int kk = 0; kk < 2; kk++) {
            s8v af[4], bfr[4];
#pragma unroll
            for (int mi = 0; mi < 4; mi++) {
                int row = wm * 64 + mi * 16 + (lane & 15);
                int byteoff = (row << 7) + ((kk * 64 + ((lane >> 4) << 4)) ^ ((row & 7) << 4));
                af[mi] = *(const s8v*)((const char*)As + byteoff);
            }
#pragma unroll
            for (int ni = 0; ni < 4; ni++) {
                int row = wn * 64 + ni * 16 + (lane & 15);
                int byteoff = (row << 7) + ((kk * 64 + ((lane >> 4) << 4)) ^ ((row & 7) << 4));
                bfr[ni] = *(const s8v*)((const char*)Bs + byteoff);
            }
#pragma unroll
            for (int mi = 0; mi < 4; mi++)
#pragma unroll
                for (int ni = 0; ni < 4; ni++)
                    acc[mi][ni] = __builtin_amdgcn_mfma_f32_16x16x32_bf16(
                        af[mi], bfr[ni], acc[mi][ni], 0, 0, 0);
        }
        __syncthreads();
    }
#pragma unroll
    for (int mi = 0; mi < 4; mi++) {
#pragma unroll
        for (int ni = 0; ni < 4; ni++) {
            int row = m0 + wm * 64 + mi * 16 + ((lane >> 4) << 2);
            int col = n0 + wn * 64 + ni * 16 + (lane & 15);
#pragma unroll
            for (int r = 0; r < 4; r++) {
                float v = acc[mi][ni][r];
                if (OUT_BF16)
                    ((unsigned short*)Cv)[(size_t)(row + r) * N + col] = f2b(v);
                else
                    ((float*)Cv)[(size_t)(row + r) * N + col] = v;
            }
        }
    }
}

// ---------------- a,b GEMM (exact f32) + g/beta: 16 rows/block ----------------
__global__ __launch_bounds__(256) void ab_gbeta_k(const float* __restrict__ x,
                                                  const float* __restrict__ Wa,
                                                  const float* __restrict__ Wb,
                                                  const float* __restrict__ dt_bias,
                                                  const float* __restrict__ A_log,
                                                  float* __restrict__ g, float* __restrict__ beta) {
    __shared__ float xr0[16 * 513];
    const int tid = threadIdx.x;
    const int r = tid & 15, cc = tid >> 4;
    const int row0 = blockIdx.x * 16;
    float a0 = 0.f, a1 = 0.f, b0 = 0.f, b1 = 0.f;
    for (int kc = 0; kc < 2048; kc += 512) {
#pragma unroll
        for (int q = 0; q < 8; q++) {
            int f = q * 256 + tid;
            int rw = f >> 7, cl = (f & 127) << 2;
            *(f4v*)&xr0[rw * 513 + cl] = *(const f4v*)(x + (size_t)(row0 + rw) * 2048 + kc + cl);
        }
        __syncthreads();
#pragma unroll 8
        for (int k = 0; k < 512; k++) {
            float xv = xr0[r * 513 + k];
            size_t kk = (size_t)(kc + k) * 32;
            a0 += xv * Wa[kk + cc];
            a1 += xv * Wa[kk + cc + 16];
            b0 += xv * Wb[kk + cc];
            b1 += xv * Wb[kk + cc + 16];
        }
        __syncthreads();
    }
    int row = row0 + r;
    float av0 = a0 + dt_bias[cc], av1 = a1 + dt_bias[cc + 16];
    float sp0 = (av0 > 20.f) ? av0 : log1pf(expf(av0));
    float sp1 = (av1 > 20.f) ? av1 : log1pf(expf(av1));
    g[(size_t)row * 32 + cc]      = -expf(A_log[cc]) * sp0;
    g[(size_t)row * 32 + cc + 16] = -expf(A_log[cc + 16]) * sp1;
    beta[(size_t)row * 32 + cc]      = 1.f / (1.f + expf(-b0));
    beta[(size_t)row * 32 + cc + 16] = 1.f / (1.f + expf(-b1));
}

// ---------------- conv + silu + l2norm + split (uint-vectorized, wave=group) ----------------
__global__ __launch_bounds__(256) void conv_fused_k(const unsigned short* __restrict__ mixp,
                                                    const float* __restrict__ convw,
                                                    unsigned short* __restrict__ qn,
                                                    unsigned short* __restrict__ kn,
                                                    unsigned short* __restrict__ vv) {
    int btid = blockIdx.x;
    int t = btid & (T_ - 1);
    int c = (blockIdx.y << 9) + (threadIdx.x << 1);   // channel pair c, c+1
    const unsigned short* base = mixp + (size_t)btid * CONV_DIM_ + c;
    unsigned m3 = *(const unsigned*)(base);
    unsigned m2 = (t >= 1) ? *(const unsigned*)(base - CONV_DIM_) : 0u;
    unsigned m1 = (t >= 2) ? *(const unsigned*)(base - 2 * CONV_DIM_) : 0u;
    unsigned m0 = (t >= 3) ? *(const unsigned*)(base - 3 * CONV_DIM_) : 0u;
    f4v w0 = *(const f4v*)(convw + (size_t)c * 4);
    f4v w1 = *(const f4v*)(convw + (size_t)c * 4 + 4);
    float v0 = b2f((unsigned short)(m3 & 0xffff)) * w0[3] + b2f((unsigned short)(m2 & 0xffff)) * w0[2]
             + b2f((unsigned short)(m1 & 0xffff)) * w0[1] + b2f((unsigned short)(m0 & 0xffff)) * w0[0];
    float v1 = b2f((unsigned short)(m3 >> 16)) * w1[3] + b2f((unsigned short)(m2 >> 16)) * w1[2]
             + b2f((unsigned short)(m1 >> 16)) * w1[1] + b2f((unsigned short)(m0 >> 16)) * w1[0];
    v0 = silu(v0); v1 = silu(v1);
    if (c < 2 * KEY_DIM_) {
        float ss = v0 * v0 + v1 * v1;
#pragma unroll
        for (int m = 1; m < 64; m <<= 1) ss += __shfl_xor(ss, m);   // 64 lanes = 128 channels = 1 group
        float scale = rsqrtf(ss + 1e-6f);
        int head = (c >> 7) & 15, d = c & 127;
        if (c < KEY_DIM_) {
            scale *= 0.08838834764831845f; // DK^-0.5
            *(unsigned*)(qn + ((size_t)btid * HK_ + head) * DK_ + d) = pk2(v0 * scale, v1 * scale);
        } else {
            *(unsigned*)(kn + ((size_t)btid * HK_ + head) * DK_ + d) = pk2(v0 * scale, v1 * scale);
        }
    } else {
        *(unsigned*)(vv + (size_t)btid * VAL_DIM_ + (c - 2 * KEY_DIM_)) = pk2(v0, v1);
    }
}

// ================= chunked delta rule: parallel precompute =================
__global__ __launch_bounds__(256) void chunk_pre_k(
    const unsigned short* __restrict__ qn, const unsigned short* __restrict__ kn,
    unsigned short* __restrict__ vv,
    const float* __restrict__ g, const float* __restrict__ beta,
    unsigned short* __restrict__ Wg, unsigned short* __restrict__ Aog,
    unsigned short* __restrict__ knT, float* __restrict__ expG, float* __restrict__ expGr)
{
    const int c = blockIdx.x, h = blockIdx.y, b = blockIdx.z;
    const int hk = h >> 1;
    const int tid = threadIdx.x, wid = tid >> 6, lane = tid & 63;
    const int r15 = lane & 15, g4 = lane >> 4;

    __shared__ __attribute__((aligned(16))) unsigned short Klds[64 * 128];
    __shared__ __attribute__((aligned(16))) unsigned short Xlds[128 * 64];
    __shared__ float AT[64][68];
    __shared__ float STmp[16][17];
    __shared__ float Gl[64], Bl[64], EG[64];

    const size_t t0 = (size_t)b * T_ + (size_t)c * 64;
    const size_t cbk = ((size_t)(b * 32 + h) * 32 + c);

    // phase a: stage K,Q swizzled (full 256B rows)
#pragma unroll
    for (int p = 0; p < 4; p++) {
        int row = p * 16 + (tid >> 4);
        int colB = (tid & 15) << 4;
        int sw = colB ^ ((row & 7) << 4);
        s8v kv = *(const s8v*)(kn + ((t0 + row) * HK_ + hk) * DK_ + (colB >> 1));
        *(s8v*)((char*)Klds + row * 256 + sw) = kv;
        s8v qv = *(const s8v*)(qn + ((t0 + row) * HK_ + hk) * DK_ + (colB >> 1));
        *(s8v*)((char*)Xlds + row * 256 + sw) = qv;
    }
    if (tid < 64) {
        Gl[tid] = g[(t0 + tid) * HV_ + h];
        Bl[tid] = beta[(t0 + tid) * HV_ + h];
    }
    __syncthreads();
    if (tid == 0) {
        float s = 0.f;
        for (int i = 0; i < 64; i++) { s += Gl[i]; Gl[i] = s; }
    }
    __syncthreads();
    if (tid < 64) {
        float Gi = Gl[tid], Gn = Gl[63];
        float e1 = expf(Gi), e2 = expf(Gn - Gi);
        EG[tid] = e1;
        expG[cbk * 64 + tid] = e1;
        expGr[cbk * 64 + tid] = e2;
    }
    __syncthreads();

    // phase b: KK = K K^T, QK = Q K^T
    f4v kkv[4], qkv[4];
#pragma unroll
    for (int jt = 0; jt < 4; jt++) { kkv[jt] = (f4v){0,0,0,0}; qkv[jt] = (f4v){0,0,0,0}; }
    const int arow = wid * 16 + r15;
#pragma unroll
    for (int ks = 0; ks < 4; ks++) {
        int abyte = arow * 256 + ((ks * 64 + (g4 << 4)) ^ ((arow & 7) << 4));
        s8v ak = *(const s8v*)((const char*)Klds + abyte);
        s8v aq = *(const s8v*)((const char*)Xlds + abyte);
#pragma unroll
        for (int jt = 0; jt < 4; jt++) {
            int jrow = jt * 16 + r15;
            int bbyte = jrow * 256 + ((ks * 64 + (g4 << 4)) ^ ((jrow & 7) << 4));
            s8v bk = *(const s8v*)((const char*)Klds + bbyte);
            kkv[jt] = __builtin_amdgcn_mfma_f32_16x16x32_bf16(ak, bk, kkv[jt], 0, 0, 0);
            qkv[jt] = __builtin_amdgcn_mfma_f32_16x16x32_bf16(aq, bk, qkv[jt], 0, 0, 0);
        }
    }
    // A build (strictly lower) + Ao write (j<=i)
#pragma unroll
    for (int jt = 0; jt < 4; jt++) {
#pragma unroll
        for (int r = 0; r < 4; r++) {
            int i = wid * 16 + g4 * 4 + r;
            int j = jt * 16 + r15;
            float em = expf(fminf(Gl[i] - Gl[j], 0.f));
            AT[i][j] = (j < i) ? Bl[i] * em * kkv[jt][r] : 0.f;
            float ao = (j <= i) ? em * qkv[jt][r] : 0.f;
            Aog[cbk * 4096 + i * 64 + j] = f2b(ao);
        }
    }
    __syncthreads();

    // phase c1: V load+scale -> Xlds ; knT write (even h, vectorized s8v stores)
    for (int u = tid; u < 1024; u += 256) {
        int row = u >> 4, v0i = (u & 15) << 3;
        s8v vx = *(const s8v*)(vv + (t0 + row) * VAL_DIM_ + h * 128 + v0i);
        float bt = Bl[row];
#pragma unroll
        for (int e = 0; e < 8; e++) {
            int v = v0i + e;
            *(unsigned short*)((char*)Xlds + v * 128 + ((row * 2) ^ ((v & 7) << 4))) =
                f2b(b2f((unsigned short)vx[e]) * bt);
        }
    }
    if ((h & 1) == 0) {
        int dk = tid & 127, th = (tid >> 7) << 5;
        size_t basek = ((size_t)(b * 16 + hk) * 128 + dk) * (size_t)T_ + (size_t)c * 64 + th;
#pragma unroll
        for (int t8 = 0; t8 < 4; t8++) {
            s8v kv;
#pragma unroll
            for (int e = 0; e < 8; e++) {
                int tt = th + t8 * 8 + e;
                kv[e] = (short)*(const unsigned short*)((const char*)Klds + tt * 256 + ((dk * 2) ^ ((tt & 7) << 4)));
            }
            *(s8v*)(knT + basek + t8 * 8) = kv;
        }
    }
    __syncthreads();

    // phase c2: blocked trisolve — diag 16x16 inverses, wave wid owns block wid
    if (lane < 16) {
        int r0 = wid * 16, col = lane;
#pragma unroll
        for (int i = 0; i < 16; i++) {
            float s = 0.f;
            for (int j = 0; j < i; j++) s += AT[r0 + i][r0 + j] * AT[r0 + j][r0 + col];
            AT[r0 + i][r0 + col] = ((col == i) ? 1.f : 0.f) - s;
        }
    }
    __syncthreads();

    // phase c3: off-diagonal blocks X_IJ = -X_II (sum_{K=J..I-1} A_IK X_KJ), ascending J
    {
        int ii = tid >> 4, jj = tid & 15;
        for (int I = 1; I < 4; I++)
            for (int J = 0; J < I; J++) {
                float s = 0.f;
                for (int K = J; K < I; K++) {
#pragma unroll
                    for (int m = 0; m < 16; m++)
                        s += AT[16 * I + ii][16 * K + m] * AT[16 * K + m][16 * J + jj];
                }
                STmp[ii][jj] = s;
                __syncthreads();
                float y = 0.f;
#pragma unroll
                for (int m = 0; m < 16; m++) y += AT[16 * I + ii][16 * I + m] * STmp[m][jj];
                __syncthreads();
                AT[16 * I + ii][16 * J + jj] = -y;
                __syncthreads();
            }
    }

    // phase d: TbV = T @ (beta V)  -> vv in place
    f4v tb[8];
#pragma unroll
    for (int vt = 0; vt < 8; vt++) tb[vt] = (f4v){0,0,0,0};
#pragma unroll
    for (int ks = 0; ks < 2; ks++) {
        s8v ta;
#pragma unroll
        for (int e = 0; e < 8; e++) ta[e] = (short)f2b(AT[arow][ks * 32 + g4 * 8 + e]);
#pragma unroll
        for (int vt = 0; vt < 8; vt++) {
            int v = vt * 16 + r15;
            int bbyte = v * 128 + ((ks * 64 + (g4 << 4)) ^ ((v & 7) << 4));
            s8v bv = *(const s8v*)((const char*)Xlds + bbyte);
            tb[vt] = __builtin_amdgcn_mfma_f32_16x16x32_bf16(ta, bv, tb[vt], 0, 0, 0);
        }
    }
#pragma unroll
    for (int vt = 0; vt < 8; vt++)
#pragma unroll
        for (int r = 0; r < 4; r++) {
            int i = wid * 16 + g4 * 4 + r, v = vt * 16 + r15;
            vv[(t0 + i) * VAL_DIM_ + h * 128 + v] = f2b(tb[vt][r]);
        }
    __syncthreads();

    // phase e: KwT[dk][t] = beta_t e^{G_t} K[t][dk]  (all 256 thr, ds_write_b128)
    {
        int dk = tid & 127;
        int tb0 = (tid >> 7) << 5;  // 0 or 32
#pragma unroll
        for (int t8 = 0; t8 < 4; t8++) {
            int tbase = tb0 + t8 * 8;
            s8v kw;
#pragma unroll
            for (int e = 0; e < 8; e++) {
                int t = tbase + e;
                float kv = b2f(*(const unsigned short*)((const char*)Klds + t * 256 + ((dk * 2) ^ ((t & 7) << 4))));
                kw[e] = (short)f2b(kv * Bl[t] * EG[t]);
            }
            *(s8v*)((char*)Xlds + dk * 128 + ((tbase * 2) ^ ((dk & 7) << 4))) = kw;
        }
    }
    __syncthreads();

    // phase f: Wmat = T @ Kw
    f4v wm[8];
#pragma unroll
    for (int dt = 0; dt < 8; dt++) wm[dt] = (f4v){0,0,0,0};
#pragma unroll
    for (int ks = 0; ks < 2; ks++) {
        s8v ta;
#pragma unroll
        for (int e = 0; e < 8; e++) ta[e] = (short)f2b(AT[arow][ks * 32 + g4 * 8 + e]);
#pragma unroll
        for (int dt = 0; dt < 8; dt++) {
            int dkr = dt * 16 + r15;
            int bbyte = dkr * 128 + ((ks * 64 + (g4 << 4)) ^ ((dkr & 7) << 4));
            s8v bw = *(const s8v*)((const char*)Xlds + bbyte);
            wm[dt] = __builtin_amdgcn_mfma_f32_16x16x32_bf16(ta, bw, wm[dt], 0, 0, 0);
        }
    }
#pragma unroll
    for (int dt = 0; dt < 8; dt++)
#pragma unroll
        for (int r = 0; r < 4; r++) {
            int i = wid * 16 + g4 * 4 + r, dk = dt * 16 + r15;
            Wg[cbk * 8192 + i * 128 + dk] = f2b(wm[dt][r]);
        }
}

// ================= chunked delta rule: sequential scan =================
__global__ __launch_bounds__(256) void chunk_scan_k(
    const unsigned short* __restrict__ qn, const unsigned short* __restrict__ knT,
    const unsigned short* __restrict__ tbv,
    const unsigned short* __restrict__ Wg, const unsigned short* __restrict__ Aog,
    const float* __restrict__ expG, const float* __restrict__ expGr,
    unsigned short* __restrict__ ob)
{
    const int bx = blockIdx.x;
    const int vq = bx & 3, h = (bx >> 2) & 31, b = bx >> 7;
    const int hk = h >> 1;
    const int tid = threadIdx.x, wid = tid >> 6, lane = tid & 63;
    const int r15 = lane & 15, g4 = lane >> 4;

    __shared__ __attribute__((aligned(16))) unsigned short Slds[32 * 128];
    __shared__ __attribute__((aligned(16))) unsigned short Ulds[32 * 64];
    __shared__ __attribute__((aligned(16))) unsigned short Uplds[32 * 64];

    f4v S[2][2];
#pragma unroll
    for (int i = 0; i < 2; i++)
#pragma unroll
        for (int j = 0; j < 2; j++) S[i][j] = (f4v){0,0,0,0};

    for (int c = 0; c < NC_; c++) {
        const size_t cbk = ((size_t)(b * 32 + h) * 32 + c);
        const size_t t0 = (size_t)b * T_ + (size_t)c * 64;

        // phase 0: stage S0 -> Slds (bf16 [v][dk], swizzled)
#pragma unroll
        for (int dkt = 0; dkt < 2; dkt++)
#pragma unroll
            for (int vt = 0; vt < 2; vt++) {
                int v = vt * 16 + r15;
                int dkb = ((wid * 2 + dkt) * 16 + g4 * 4) * 2;
                int sw = (v & 7) << 4;
                *(unsigned int*)((char*)Slds + v * 256 + ((dkb) ^ sw))     = pk2(S[dkt][vt][0], S[dkt][vt][1]);
                *(unsigned int*)((char*)Slds + v * 256 + ((dkb + 4) ^ sw)) = pk2(S[dkt][vt][2], S[dkt][vt][3]);
            }
        __syncthreads();

        // phase 1: P = Wmat @ S0 ; U = TbV - P -> Ulds, U' -> Uplds
        f4v P[2]; P[0] = (f4v){0,0,0,0}; P[1] = (f4v){0,0,0,0};
        s8v sf[4][2];
        const unsigned short* wp = Wg + cbk * 8192 + (size_t)(wid * 16 + r15) * 128;
#pragma unroll
        for (int ks = 0; ks < 4; ks++) {
            s8v aw = *(const s8v*)(wp + ks * 32 + g4 * 8);
#pragma unroll
            for (int vt = 0; vt < 2; vt++) {
                int v = vt * 16 + r15;
                sf[ks][vt] = *(const s8v*)((const char*)Slds + v * 256 + ((ks * 64 + g4 * 16) ^ ((v & 7) << 4)));
                P[vt] = __builtin_amdgcn_mfma_f32_16x16x32_bf16(aw, sf[ks][vt], P[vt], 0, 0, 0);
            }
        }
        float egr[4];
#pragma unroll
        for (int r = 0; r < 4; r++) egr[r] = expGr[cbk * 64 + wid * 16 + g4 * 4 + r];
#pragma unroll
        for (int vt = 0; vt < 2; vt++) {
            float uu[4], up[4];
#pragma unroll
            for (int r = 0; r < 4; r++) {
                int t = wid * 16 + g4 * 4 + r;
                unsigned short tv = tbv[(t0 + t) * VAL_DIM_ + h * 128 + vq * 32 + vt * 16 + r15];
                uu[r] = b2f(tv) - P[vt][r];
                up[r] = uu[r] * egr[r];
            }
            int v = vt * 16 + r15;
            int tb2 = (wid * 16 + g4 * 4) * 2;
            int sw = (v & 7) << 4;
            *(unsigned int*)((char*)Ulds  + v * 128 + ((tb2) ^ sw))     = pk2(uu[0], uu[1]);
            *(unsigned int*)((char*)Ulds  + v * 128 + ((tb2 + 4) ^ sw)) = pk2(uu[2], uu[3]);
            *(unsigned int*)((char*)Uplds + v * 128 + ((tb2) ^ sw))     = pk2(up[0], up[1]);
            *(unsigned int*)((char*)Uplds + v * 128 + ((tb2 + 4) ^ sw)) = pk2(up[2], up[3]);
        }
        __syncthreads();

        // phase 2: O = (e^G q) @ S0 + Ao @ U
        f4v O[2]; O[0] = (f4v){0,0,0,0}; O[1] = (f4v){0,0,0,0};
        float egi = expG[cbk * 64 + wid * 16 + r15];
        const unsigned short* qp = qn + ((t0 + wid * 16 + r15) * HK_ + hk) * DK_;
#pragma unroll
        for (int ks = 0; ks < 4; ks++) {
            s8v q0 = *(const s8v*)(qp + ks * 32 + g4 * 8);
            s8v qg;
#pragma unroll
            for (int e = 0; e < 8; e++) qg[e] = (short)f2b(b2f((unsigned short)q0[e]) * egi);
#pragma unroll
            for (int vt = 0; vt < 2; vt++)
                O[vt] = __builtin_amdgcn_mfma_f32_16x16x32_bf16(qg, sf[ks][vt], O[vt], 0, 0, 0);
        }
        const unsigned short* ap = Aog + cbk * 4096 + (size_t)(wid * 16 + r15) * 64;
#pragma unroll
        for (int ks = 0; ks < 2; ks++) {
            s8v aa = *(const s8v*)(ap + ks * 32 + g4 * 8);
#pragma unroll
            for (int vt = 0; vt < 2; vt++) {
                int v = vt * 16 + r15;
                s8v bu = *(const s8v*)((const char*)Ulds + v * 128 + ((ks * 64 + g4 * 16) ^ ((v & 7) << 4)));
                O[vt] = __builtin_amdgcn_mfma_f32_16x16x32_bf16(aa, bu, O[vt], 0, 0, 0);
            }
        }
#pragma unroll
        for (int vt = 0; vt < 2; vt++)
#pragma unroll
            for (int r = 0; r < 4; r++) {
                int t = c * 64 + wid * 16 + g4 * 4 + r;
                ob[((size_t)b * T_ + t) * VAL_DIM_ + h * 128 + vq * 32 + vt * 16 + r15] = f2b(O[vt][r]);
            }

        // phase 3: S = gamma*S + knT @ U'
        float gam = expG[cbk * 64 + 63];
#pragma unroll
        for (int dkt = 0; dkt < 2; dkt++)
#pragma unroll
            for (int vt = 0; vt < 2; vt++) {
                S[dkt][vt][0] *= gam; S[dkt][vt][1] *= gam;
                S[dkt][vt][2] *= gam; S[dkt][vt][3] *= gam;
            }
        const unsigned short* kp = knT + ((size_t)(b * 16 + hk) * 128) * (size_t)T_;
#pragma unroll
        for (int ks = 0; ks < 2; ks++) {
            s8v bu[2];
#pragma unroll
            for (int vt = 0; vt < 2; vt++) {
                int v = vt * 16 + r15;
                bu[vt] = *(const s8v*)((const char*)Uplds + v * 128 + ((ks * 64 + g4 * 16) ^ ((v & 7) << 4)));
            }
#pragma unroll
            for (int dkt = 0; dkt < 2; dkt++) {
                s8v ak = *(const s8v*)(kp + (size_t)((wid * 2 + dkt) * 16 + r15) * T_ + (size_t)c * 64 + ks * 32 + g4 * 8);
#pragma unroll
                for (int vt = 0; vt < 2; vt++)
                    S[dkt][vt] = __builtin_amdgcn_mfma_f32_16x16x32_bf16(ak, bu[vt], S[dkt][vt], 0, 0, 0);
            }
        }
        __syncthreads();
    }
}

// ---------------- gated RMSNorm + silu(z) gate: wave-per-head, uint loads ----------------
__global__ __launch_bounds__(256) void norm_gate_k(unsigned short* __restrict__ o,
                                                   const unsigned short* __restrict__ z,
                                                   const float* __restrict__ nw) {
    int lane = threadIdx.x & 63;
    size_t bh = (size_t)blockIdx.x * 4 + (threadIdx.x >> 6);
    unsigned ov = *(unsigned*)(o + bh * 128 + lane * 2);
    float v0 = b2f((unsigned short)(ov & 0xffff)), v1 = b2f((unsigned short)(ov >> 16));
    float ss = v0 * v0 + v1 * v1;
#pragma unroll
    for (int m = 1; m < 64; m <<= 1) ss += __shfl_xor(ss, m);
    float rr = rsqrtf(ss * (1.f / 128.f) + 1e-6f);
    unsigned zv = *(const unsigned*)(z + bh * 128 + lane * 2);
    float z0 = b2f((unsigned short)(zv & 0xffff)), z1 = b2f((unsigned short)(zv >> 16));
    float o0 = v0 * rr * nw[lane * 2]     * silu(z0);
    float o1 = v1 * rr * nw[lane * 2 + 1] * silu(z1);
    *(unsigned*)(o + bh * 128 + lane * 2) = pk2(o0, o1);
}

// ---------------- launch ----------------
// ws regions (MB = 1<<20), total ~194MB:
//  @0-64:   mixp | then Wmat[0:32) knT[32:48) Aog[48:64)
//  @64-96:  WqkvT | kn@[80:96) (conv->pre) | obuf (contiguous 32MB, scan->norm->gemm)
//  @96-112: WzT -> WoutT
//  @112-128: xb -> qn
//  @128-160: vv -> TbV (in place)
//  @160-192: zb
//  @192+:   gbuf, bbuf, expG, expGr
extern "C" void kernel_launch(void* const* d_in, const int* in_sizes, int n_in,
                              void* d_out, int out_size, void* d_ws, size_t ws_size,
                              hipStream_t stream) {
    const float* x      = (const float*)d_in[0];
    const float* W_qkv  = (const float*)d_in[1];
    const float* W_z    = (const float*)d_in[2];
    const float* W_a    = (const float*)d_in[3];
    const float* W_b    = (const float*)d_in[4];
    const float* W_out  = (const float*)d_in[5];
    const float* conv_w = (const float*)d_in[6];
    const float* dt_bias= (const float*)d_in[7];
    const float* A_log  = (const float*)d_in[8];
    const float* norm_w = (const float*)d_in[9];

    char* w = (char*)d_ws;
    const size_t MBc = (size_t)1 << 20;
    unsigned short* mixp  = (unsigned short*)(w);
    unsigned short* Wmat  = (unsigned short*)(w);
    unsigned short* knT   = (unsigned short*)(w + 32 * MBc);
    unsigned short* Aog   = (unsigned short*)(w + 48 * MBc);
    unsigned short* WqkvT = (unsigned short*)(w + 64 * MBc);
    unsigned short* obuf  = (unsigned short*)(w + 64 * MBc);
    unsigned short* kn    = (unsigned short*)(w + 80 * MBc);
    unsigned short* WzT   = (unsigned short*)(w + 96 * MBc);
    unsigned short* WoutT = (unsigned short*)(w + 96 * MBc);
    unsigned short* xb    = (unsigned short*)(w + 112 * MBc);
    unsigned short* qn    = (unsigned short*)(w + 112 * MBc);
    unsigned short* vv    = (unsigned short*)(w + 128 * MBc);
    unsigned short* zb    = (unsigned short*)(w + 160 * MBc);
    float* gbuf  = (float*)(w + 192 * MBc);
    float* bbuf  = (float*)(w + 192 * MBc + 512 * 1024);
    float* expG  = (float*)(w + 192 * MBc + 1024 * 1024);
    float* expGr = (float*)(w + 192 * MBc + 1536 * 1024);

    cast_bf16_k<<<(BT_ * DIM_ / 8 + 255) / 256, 256, 0, stream>>>(x, xb, BT_ * DIM_ / 8);
    transpose_cast_k<<<dim3(CONV_DIM_ / 32, DIM_ / 32), 256, 0, stream>>>(W_qkv, WqkvT, DIM_, CONV_DIM_);
    transpose_cast_k<<<dim3(VAL_DIM_ / 32, DIM_ / 32), 256, 0, stream>>>(W_z, WzT, DIM_, VAL_DIM_);
    gemm_bt_k<1><<<dim3(CONV_DIM_ / 128, BT_ / 128), 256, 0, stream>>>(xb, WqkvT, mixp, BT_, CONV_DIM_, DIM_);
    gemm_bt_k<1><<<dim3(VAL_DIM_ / 128, BT_ / 128), 256, 0, stream>>>(xb, WzT, zb, BT_, VAL_DIM_, DIM_);
    transpose_cast_k<<<dim3(DIM_ / 32, VAL_DIM_ / 32), 256, 0, stream>>>(W_out, WoutT, VAL_DIM_, DIM_);
    ab_gbeta_k<<<BT_ / 16, 256, 0, stream>>>(x, W_a, W_b, dt_bias, A_log, gbuf, bbuf);
    conv_fused_k<<<dim3(BT_, CONV_DIM_ / 512), 256, 0, stream>>>(mixp, conv_w, qn, kn, vv);
    chunk_pre_k<<<dim3(NC_, HV_, B_), 256, 0, stream>>>(qn, kn, vv, gbuf, bbuf,
                                                        Wmat, Aog, knT, expG, expGr);
    chunk_scan_k<<<B_ * HV_ * 4, 256, 0, stream>>>(qn, knT, vv, Wmat, Aog, expG, expGr, obuf);
    norm_gate_k<<<BT_ * HV_ / 4, 256, 0, stream>>>(obuf, zb, norm_w);
    gemm_bt_k<0><<<dim3(DIM_ / 128, BT_ / 128), 256, 0, stream>>>(obuf, WoutT, d_out, BT_, DIM_, VAL_DIM_);
}